// Round 1
// baseline (678.913 us; speedup 1.0000x reference)
//
#include <hip/hip_runtime.h>

// GraphSAGE 2-layer inference, fp32.
// Pipeline: detect edge dtype -> transpose weights -> CSR build (hist/scan/fill)
//  -> agg1 = A_mean * x  (gather, wave-per-node, float2 lanes)
//  -> fused MLP: g = relu(agg1 @ W1T + b1) @ W2T   (register-tiled fp32 GEMM)
//  -> agg2 = A_mean * g + b2 -> log_softmax  (gather, quarter-wave float4, fused epilogue)
// Uses linear-commutes-with-mean: layer2 projects 256->64 BEFORE aggregation (4x less gather).

#define WN 100000
#define WE 1600000

__global__ void __launch_bounds__(64) k_detect(const int* __restrict__ ei, int* __restrict__ flag) {
  // int64 edge data (values < 2^31) => every odd int32 word is 0.
  int t = threadIdx.x;
  int v = ei[2 * t + 1];
  unsigned long long m = __ballot(v != 0);
  if (t == 0) *flag = (m == 0ull) ? 1 : 0;
}

__global__ void __launch_bounds__(256) k_transpose(const float* __restrict__ W1, const float* __restrict__ W2,
                                                   float* __restrict__ W1T, float* __restrict__ W2T) {
  int idx = blockIdx.x * 256 + threadIdx.x;
  if (idx < 256 * 128) {
    int j = idx >> 7, k = idx & 127;
    W1T[k * 256 + j] = W1[idx];          // W1T[128][256]
  } else {
    int i2 = idx - 32768;
    if (i2 < 64 * 256) {
      int o = i2 >> 8, j = i2 & 255;
      W2T[j * 64 + o] = W2[i2];          // W2T[256][64]
    }
  }
}

__global__ void __launch_bounds__(256) k_hist(const int* __restrict__ ei, const int* __restrict__ flag,
                                              int* __restrict__ deg, int E) {
  int e = blockIdx.x * 256 + threadIdx.x;
  if (e >= E) return;
  int d;
  if (*flag) d = (int)((const long long*)ei)[(size_t)E + e];
  else       d = ei[(size_t)E + e];
  atomicAdd(&deg[d], 1);
}

__global__ void __launch_bounds__(256) k_partial(const int* __restrict__ deg, int* __restrict__ part, int N) {
  int b = blockIdx.x, t = threadIdx.x;
  int base = b * 1024;
  int s = 0;
#pragma unroll
  for (int q = 0; q < 4; ++q) {
    int i = base + q * 256 + t;
    if (i < N) s += deg[i];
  }
#pragma unroll
  for (int off = 32; off; off >>= 1) s += __shfl_down(s, off);
  __shared__ int ws[4];
  if ((t & 63) == 0) ws[t >> 6] = s;
  __syncthreads();
  if (t == 0) part[b] = ws[0] + ws[1] + ws[2] + ws[3];
}

__global__ void __launch_bounds__(128) k_scan_part(int* __restrict__ part, int* __restrict__ row_ptr, int NB, int N) {
  __shared__ int lds[128];
  int t = threadIdx.x;
  int v = (t < NB) ? part[t] : 0;
  lds[t] = v;
  __syncthreads();
  for (int o = 1; o < 128; o <<= 1) {
    int u = (t >= o) ? lds[t - o] : 0;
    __syncthreads();
    lds[t] += u;
    __syncthreads();
  }
  if (t < NB) part[t] = (t ? lds[t - 1] : 0);
  if (t == 0) row_ptr[N] = lds[127];  // == E
}

__global__ void __launch_bounds__(256) k_scan_final(const int* __restrict__ deg, const int* __restrict__ part,
                                                    int* __restrict__ row_ptr, int* __restrict__ rp_mut,
                                                    float* __restrict__ inv_deg, int N) {
  int b = blockIdx.x, t = threadIdx.x;
  int base = b * 1024 + t * 4;
  int d0 = 0, d1 = 0, d2 = 0, d3 = 0;
  if (base + 3 < N) {
    int4 v = *(const int4*)(deg + base);
    d0 = v.x; d1 = v.y; d2 = v.z; d3 = v.w;
  } else {
    if (base + 0 < N) d0 = deg[base + 0];
    if (base + 1 < N) d1 = deg[base + 1];
    if (base + 2 < N) d2 = deg[base + 2];
    if (base + 3 < N) d3 = deg[base + 3];
  }
  __shared__ int lds[256];
  lds[t] = d0 + d1 + d2 + d3;
  __syncthreads();
  for (int o = 1; o < 256; o <<= 1) {
    int u = (t >= o) ? lds[t - o] : 0;
    __syncthreads();
    lds[t] += u;
    __syncthreads();
  }
  int ex = (t ? lds[t - 1] : 0) + part[b];
  int e0 = ex, e1 = ex + d0, e2 = e1 + d1, e3 = e2 + d2;
  int es[4] = {e0, e1, e2, e3};
  int ds[4] = {d0, d1, d2, d3};
#pragma unroll
  for (int r = 0; r < 4; ++r) {
    int i = base + r;
    if (i < N) {
      row_ptr[i] = es[r];
      rp_mut[i] = es[r];
      inv_deg[i] = 1.0f / (float)(ds[r] > 0 ? ds[r] : 1);
    }
  }
}

__global__ void __launch_bounds__(256) k_fill(const int* __restrict__ ei, const int* __restrict__ flag,
                                              int* __restrict__ rp_mut, int* __restrict__ csr, int E) {
  int e = blockIdx.x * 256 + threadIdx.x;
  if (e >= E) return;
  int s, d;
  if (*flag) {
    const long long* p = (const long long*)ei;
    s = (int)p[e];
    d = (int)p[(size_t)E + e];
  } else {
    s = ei[e];
    d = ei[(size_t)E + e];
  }
  int pos = atomicAdd(&rp_mut[d], 1);
  csr[pos] = s;
}

// agg1[n] = inv_deg[n] * sum_{e in row n} x[csr[e]]   (128 dims, float2 per lane)
__global__ void __launch_bounds__(256) k_agg1(const float2* __restrict__ x2, const int* __restrict__ csr,
                                              const int* __restrict__ row_ptr, const float* __restrict__ inv_deg,
                                              float2* __restrict__ agg1, int N) {
  int n = blockIdx.x * 4 + (threadIdx.x >> 6);
  if (n >= N) return;
  int l = threadIdx.x & 63;
  int s = row_ptr[n], e = row_ptr[n + 1];
  float2 a0 = make_float2(0.f, 0.f), a1 = make_float2(0.f, 0.f);
  int i = s;
  for (; i + 1 < e; i += 2) {
    int s0 = csr[i], s1 = csr[i + 1];
    float2 v0 = x2[(size_t)s0 * 64 + l];
    float2 v1 = x2[(size_t)s1 * 64 + l];
    a0.x += v0.x; a0.y += v0.y;
    a1.x += v1.x; a1.y += v1.y;
  }
  if (i < e) {
    float2 v = x2[(size_t)csr[i] * 64 + l];
    a0.x += v.x; a0.y += v.y;
  }
  float inv = inv_deg[n];
  float2 r;
  r.x = (a0.x + a1.x) * inv;
  r.y = (a0.y + a1.y) * inv;
  agg1[(size_t)n * 64 + l] = r;
}

// Fused per-node MLP: g = relu(agg1 @ W1T + b1) @ W2T
// Block: 256 threads, 32 nodes. GEMM1 micro-tile 4x8, GEMM2 4x2.
__global__ void __launch_bounds__(256) k_mlp(const float* __restrict__ agg, const float* __restrict__ W1T,
                                             const float* __restrict__ b1, const float* __restrict__ W2T,
                                             float* __restrict__ g, int N) {
  __shared__ __align__(16) char smem_raw[49280];
  float* aT  = (float*)smem_raw;             // phase1: [32][129]
  float* w1t = (float*)(smem_raw + 16512);   // phase1: [32][256]
  float* hT  = (float*)smem_raw;             // phase2: [32][257]
  float* w2t = (float*)(smem_raw + 32896);   // phase2: [64][64]
  const int t = threadIdx.x;
  const int n0 = blockIdx.x * 32;

  // stage agg tile [32][128] -> aT[n][k], pad 129 (conflict-free scalar access)
  {
    const float4* src = (const float4*)(agg + (size_t)n0 * 128);
#pragma unroll
    for (int i = 0; i < 4; ++i) {
      int idx4 = i * 256 + t;
      float4 v = src[idx4];
      int n = idx4 >> 5, k = (idx4 & 31) << 2;
      float* d = aT + n * 129 + k;
      d[0] = v.x; d[1] = v.y; d[2] = v.z; d[3] = v.w;
    }
  }
  const int jg = t & 31, mg = t >> 5;
  const int j0 = jg << 3, m0 = mg << 2;
  float acc[4][8];
#pragma unroll
  for (int i = 0; i < 4; ++i)
#pragma unroll
    for (int r = 0; r < 8; ++r) acc[i][r] = 0.f;

#pragma unroll 1
  for (int kt = 0; kt < 4; ++kt) {
    __syncthreads();
    const float4* src = (const float4*)(W1T + kt * 8192);
#pragma unroll
    for (int i = 0; i < 8; ++i) ((float4*)w1t)[i * 256 + t] = src[i * 256 + t];
    __syncthreads();
#pragma unroll 8
    for (int kk = 0; kk < 32; ++kk) {
      int k = kt * 32 + kk;
      float a[4];
#pragma unroll
      for (int i = 0; i < 4; ++i) a[i] = aT[(m0 + i) * 129 + k];
      float4 wA = *(const float4*)(w1t + kk * 256 + j0);
      float4 wB = *(const float4*)(w1t + kk * 256 + j0 + 4);
      float w[8] = {wA.x, wA.y, wA.z, wA.w, wB.x, wB.y, wB.z, wB.w};
#pragma unroll
      for (int i = 0; i < 4; ++i)
#pragma unroll
        for (int r = 0; r < 8; ++r) acc[i][r] += a[i] * w[r];
    }
  }
  __syncthreads();  // done reading aT/w1t; hT overlaps them
  {
    float4 bA = *(const float4*)(b1 + j0);
    float4 bB = *(const float4*)(b1 + j0 + 4);
    float bb[8] = {bA.x, bA.y, bA.z, bA.w, bB.x, bB.y, bB.z, bB.w};
#pragma unroll
    for (int i = 0; i < 4; ++i)
#pragma unroll
      for (int r = 0; r < 8; ++r) {
        float hv = acc[i][r] + bb[r];
        hT[(m0 + i) * 257 + j0 + r] = fmaxf(hv, 0.f);
      }
  }
  __syncthreads();

  const int og = t & 31;
  const int o0 = og << 1;
  float acc2[4][2];
#pragma unroll
  for (int i = 0; i < 4; ++i) { acc2[i][0] = 0.f; acc2[i][1] = 0.f; }

#pragma unroll 1
  for (int jt = 0; jt < 4; ++jt) {
    if (jt) __syncthreads();
    const float4* src = (const float4*)(W2T + jt * 4096);
#pragma unroll
    for (int i = 0; i < 4; ++i) ((float4*)w2t)[i * 256 + t] = src[i * 256 + t];
    __syncthreads();
#pragma unroll 8
    for (int jj = 0; jj < 64; ++jj) {
      int j = jt * 64 + jj;
      float h0 = hT[(m0 + 0) * 257 + j];
      float h1 = hT[(m0 + 1) * 257 + j];
      float h2 = hT[(m0 + 2) * 257 + j];
      float h3 = hT[(m0 + 3) * 257 + j];
      float2 w = *(const float2*)(w2t + jj * 64 + o0);
      acc2[0][0] += h0 * w.x; acc2[0][1] += h0 * w.y;
      acc2[1][0] += h1 * w.x; acc2[1][1] += h1 * w.y;
      acc2[2][0] += h2 * w.x; acc2[2][1] += h2 * w.y;
      acc2[3][0] += h3 * w.x; acc2[3][1] += h3 * w.y;
    }
  }
  float2* gp = (float2*)(g + (size_t)n0 * 64);
#pragma unroll
  for (int i = 0; i < 4; ++i) gp[(m0 + i) * 32 + og] = make_float2(acc2[i][0], acc2[i][1]);
}

// agg2 + b2 + log_softmax fused. Wave per node; quarter-wave (16 lanes) per edge, float4/lane.
__global__ void __launch_bounds__(256) k_agg2(const float4* __restrict__ g4, const int* __restrict__ csr,
                                              const int* __restrict__ row_ptr, const float* __restrict__ inv_deg,
                                              const float4* __restrict__ b2v, float4* __restrict__ out4, int N) {
  int n = blockIdx.x * 4 + (threadIdx.x >> 6);
  if (n >= N) return;
  int lane = threadIdx.x & 63;
  int gq = lane >> 4, p = lane & 15;
  int s = row_ptr[n], e = row_ptr[n + 1];
  float4 acc = make_float4(0.f, 0.f, 0.f, 0.f);
  for (int i = s + gq; i < e; i += 4) {
    int src = csr[i];
    float4 v = g4[(size_t)src * 16 + p];
    acc.x += v.x; acc.y += v.y; acc.z += v.z; acc.w += v.w;
  }
  // reduce the 4 quarter-wave groups
  acc.x += __shfl_xor(acc.x, 16); acc.y += __shfl_xor(acc.y, 16);
  acc.z += __shfl_xor(acc.z, 16); acc.w += __shfl_xor(acc.w, 16);
  acc.x += __shfl_xor(acc.x, 32); acc.y += __shfl_xor(acc.y, 32);
  acc.z += __shfl_xor(acc.z, 32); acc.w += __shfl_xor(acc.w, 32);
  float inv = inv_deg[n];
  float4 b = b2v[p];
  float4 v;
  v.x = acc.x * inv + b.x;
  v.y = acc.y * inv + b.y;
  v.z = acc.z * inv + b.z;
  v.w = acc.w * inv + b.w;
  // log_softmax over the 64 values (distributed across p=0..15, 4 per lane)
  float mx = fmaxf(fmaxf(v.x, v.y), fmaxf(v.z, v.w));
#pragma unroll
  for (int off = 1; off <= 8; off <<= 1) mx = fmaxf(mx, __shfl_xor(mx, off));
  float se = expf(v.x - mx) + expf(v.y - mx) + expf(v.z - mx) + expf(v.w - mx);
#pragma unroll
  for (int off = 1; off <= 8; off <<= 1) se += __shfl_xor(se, off);
  float lse = mx + logf(se);
  v.x -= lse; v.y -= lse; v.z -= lse; v.w -= lse;
  if (gq == 0) out4[(size_t)n * 16 + p] = v;
}

extern "C" void kernel_launch(void* const* d_in, const int* in_sizes, int n_in,
                              void* d_out, int out_size, void* d_ws, size_t ws_size,
                              hipStream_t stream) {
  const float* x  = (const float*)d_in[0];
  const int*   ei = (const int*)d_in[1];
  const float* W1 = (const float*)d_in[2];
  const float* b1 = (const float*)d_in[3];
  const float* W2 = (const float*)d_in[4];
  const float* b2 = (const float*)d_in[5];
  float* out = (float*)d_out;
  const int N = in_sizes[0] / 128;  // 100000
  const int E = in_sizes[1] / 2;    // 1600000

  char* base = (char*)d_ws;
  size_t off = 0;
  auto alloc = [&](size_t bytes) -> char* {
    char* p = base + off;
    off += (bytes + 255) & ~(size_t)255;
    return p;
  };
  int*   flag    = (int*)alloc(4);
  int*   deg     = (int*)alloc((size_t)N * 4);
  int*   part    = (int*)alloc(1024);
  int*   row_ptr = (int*)alloc((size_t)(N + 1) * 4);
  int*   rp_mut  = (int*)alloc((size_t)N * 4);
  float* inv_deg = (float*)alloc((size_t)N * 4);
  int*   csr     = (int*)alloc((size_t)E * 4);
  float* W1T     = (float*)alloc((size_t)128 * 256 * 4);
  float* W2T     = (float*)alloc((size_t)256 * 64 * 4);
  float* agg1    = (float*)alloc((size_t)N * 128 * 4);
  float* g       = (float*)alloc((size_t)N * 64 * 4);
  (void)ws_size; (void)n_in; (void)out_size;

  hipMemsetAsync(deg, 0, (size_t)N * 4, stream);
  k_detect<<<1, 64, 0, stream>>>(ei, flag);
  k_transpose<<<192, 256, 0, stream>>>(W1, W2, W1T, W2T);
  k_hist<<<(E + 255) / 256, 256, 0, stream>>>(ei, flag, deg, E);
  int NB = (N + 1023) / 1024;  // 98
  k_partial<<<NB, 256, 0, stream>>>(deg, part, N);
  k_scan_part<<<1, 128, 0, stream>>>(part, row_ptr, NB, N);
  k_scan_final<<<NB, 256, 0, stream>>>(deg, part, row_ptr, rp_mut, inv_deg, N);
  k_fill<<<(E + 255) / 256, 256, 0, stream>>>(ei, flag, rp_mut, csr, E);
  k_agg1<<<(N + 3) / 4, 256, 0, stream>>>((const float2*)x, csr, row_ptr, inv_deg, (float2*)agg1, N);
  k_mlp<<<(N + 31) / 32, 256, 0, stream>>>(agg1, W1T, b1, W2T, g, N);
  k_agg2<<<(N + 3) / 4, 256, 0, stream>>>((const float4*)g, csr, row_ptr, inv_deg, (const float4*)b2,
                                          (float4*)out, N);
}

// Round 3
// 497.309 us; speedup vs baseline: 1.3652x; 1.3652x over previous
//
#include <hip/hip_runtime.h>

// GraphSAGE 2-layer inference.
// Pipeline: detect edge dtype -> prep (x->bf16, W1/W2 -> MFMA-fragment-ordered bf16)
//  -> CSR build (hist/scan/fill)
//  -> agg1 = A_mean * x_bf16        (gather, half-wave ushort4 lanes, fp32 accum, bf16 out)
//  -> fused MLP (bf16 MFMA): g = relu(agg1 @ W1T + b1) @ W2T  -> bf16
//  -> agg2 = A_mean * g + b2 -> log_softmax (gather bf16, fp32 out)
// Linear-commutes-with-mean: layer2 projects 256->64 BEFORE aggregation (4x less gather).

typedef __attribute__((ext_vector_type(8))) short bf16x8;
typedef __attribute__((ext_vector_type(4))) float f32x4;

__device__ inline ushort f2bf(float f) {
  union { float f; unsigned u; } c; c.f = f;
  unsigned r = (c.u + 0x7fffu + ((c.u >> 16) & 1u)) >> 16;
  return (ushort)r;
}
__device__ inline float bf2f(ushort u) {
  union { unsigned u; float f; } c; c.u = ((unsigned)u) << 16;
  return c.f;
}

__global__ void __launch_bounds__(64) k_detect(const int* __restrict__ ei, int* __restrict__ flag) {
  // int64 edge data (values < 2^31) => every odd int32 word is 0.
  int t = threadIdx.x;
  int v = ei[2 * t + 1];
  unsigned long long m = __ballot(v != 0);
  if (t == 0) *flag = (m == 0ull) ? 1 : 0;
}

// x fp32 -> bf16
__global__ void __launch_bounds__(256) k_prep_x(const float4* __restrict__ x4, ushort4* __restrict__ xb4, int total4) {
  int i = blockIdx.x * 256 + threadIdx.x;
  if (i >= total4) return;
  float4 v = x4[i];
  ushort4 o;
  o.x = f2bf(v.x); o.y = f2bf(v.y); o.z = f2bf(v.z); o.w = f2bf(v.w);
  xb4[i] = o;
}

// W1[256][128], W2[64][256] -> bf16 MFMA B-fragment order.
// 16x16x32 bf16 B-frag: lane l holds B[k = kt*32 + (l>>4)*8 + e][n = nt*16 + (l&15)], e=0..7.
// W1f[((jt*4+kt)*64 + l)*8 + e] = W1[j][k];  jt in [0,16), kt in [0,4)
// W2f[((ot*8+kt)*64 + l)*8 + e] = W2[o][k];  ot in [0,4),  kt in [0,8)
__global__ void __launch_bounds__(256) k_prep_w(const float* __restrict__ W1, const float* __restrict__ W2,
                                                ushort* __restrict__ W1f, ushort* __restrict__ W2f) {
  int idx = blockIdx.x * 256 + threadIdx.x;
  if (idx < 32768) {
    int jt = idx >> 11, rem = idx & 2047;
    int kt = rem >> 9, rem2 = rem & 511;
    int l = rem2 >> 3, e = rem2 & 7;
    int k = kt * 32 + (l >> 4) * 8 + e;
    int j = jt * 16 + (l & 15);
    W1f[idx] = f2bf(W1[j * 128 + k]);
  } else {
    int i2 = idx - 32768;
    if (i2 < 16384) {
      int ot = i2 >> 12, rem = i2 & 4095;
      int kt = rem >> 9;
      int l = (rem >> 3) & 63, e = rem & 7;
      int k = kt * 32 + (l >> 4) * 8 + e;
      int o = ot * 16 + (l & 15);
      W2f[i2] = f2bf(W2[o * 256 + k]);
    }
  }
}

__global__ void __launch_bounds__(256) k_hist(const int* __restrict__ ei, const int* __restrict__ flag,
                                              int* __restrict__ deg, int E) {
  int e = blockIdx.x * 256 + threadIdx.x;
  if (e >= E) return;
  int d;
  if (*flag) d = (int)((const long long*)ei)[(size_t)E + e];
  else       d = ei[(size_t)E + e];
  atomicAdd(&deg[d], 1);
}

__global__ void __launch_bounds__(256) k_partial(const int* __restrict__ deg, int* __restrict__ part, int N) {
  int b = blockIdx.x, t = threadIdx.x;
  int base = b * 1024;
  int s = 0;
#pragma unroll
  for (int q = 0; q < 4; ++q) {
    int i = base + q * 256 + t;
    if (i < N) s += deg[i];
  }
#pragma unroll
  for (int off = 32; off; off >>= 1) s += __shfl_down(s, off);
  __shared__ int ws[4];
  if ((t & 63) == 0) ws[t >> 6] = s;
  __syncthreads();
  if (t == 0) part[b] = ws[0] + ws[1] + ws[2] + ws[3];
}

__global__ void __launch_bounds__(128) k_scan_part(int* __restrict__ part, int* __restrict__ row_ptr, int NB, int N) {
  __shared__ int lds[128];
  int t = threadIdx.x;
  int v = (t < NB) ? part[t] : 0;
  lds[t] = v;
  __syncthreads();
  for (int o = 1; o < 128; o <<= 1) {
    int u = (t >= o) ? lds[t - o] : 0;
    __syncthreads();
    lds[t] += u;
    __syncthreads();
  }
  if (t < NB) part[t] = (t ? lds[t - 1] : 0);
  if (t == 0) row_ptr[N] = lds[127];  // == E
}

__global__ void __launch_bounds__(256) k_scan_final(const int* __restrict__ deg, const int* __restrict__ part,
                                                    int* __restrict__ row_ptr, int* __restrict__ rp_mut,
                                                    float* __restrict__ inv_deg, int N) {
  int b = blockIdx.x, t = threadIdx.x;
  int base = b * 1024 + t * 4;
  int d0 = 0, d1 = 0, d2 = 0, d3 = 0;
  if (base + 3 < N) {
    int4 v = *(const int4*)(deg + base);
    d0 = v.x; d1 = v.y; d2 = v.z; d3 = v.w;
  } else {
    if (base + 0 < N) d0 = deg[base + 0];
    if (base + 1 < N) d1 = deg[base + 1];
    if (base + 2 < N) d2 = deg[base + 2];
    if (base + 3 < N) d3 = deg[base + 3];
  }
  __shared__ int lds[256];
  lds[t] = d0 + d1 + d2 + d3;
  __syncthreads();
  for (int o = 1; o < 256; o <<= 1) {
    int u = (t >= o) ? lds[t - o] : 0;
    __syncthreads();
    lds[t] += u;
    __syncthreads();
  }
  int ex = (t ? lds[t - 1] : 0) + part[b];
  int e0 = ex, e1 = ex + d0, e2 = e1 + d1, e3 = e2 + d2;
  int es[4] = {e0, e1, e2, e3};
  int ds[4] = {d0, d1, d2, d3};
#pragma unroll
  for (int r = 0; r < 4; ++r) {
    int i = base + r;
    if (i < N) {
      row_ptr[i] = es[r];
      rp_mut[i] = es[r];
      inv_deg[i] = 1.0f / (float)(ds[r] > 0 ? ds[r] : 1);
    }
  }
}

__global__ void __launch_bounds__(256) k_fill(const int* __restrict__ ei, const int* __restrict__ flag,
                                              int* __restrict__ rp_mut, int* __restrict__ csr, int E) {
  int e = blockIdx.x * 256 + threadIdx.x;
  if (e >= E) return;
  int s, d;
  if (*flag) {
    const long long* p = (const long long*)ei;
    s = (int)p[e];
    d = (int)p[(size_t)E + e];
  } else {
    s = ei[e];
    d = ei[(size_t)E + e];
  }
  int pos = atomicAdd(&rp_mut[d], 1);
  csr[pos] = s;
}

// agg1b[n] = bf16( inv_deg[n] * sum_{e in row n} xb[csr[e]] )
// wave per node; half-wave (32 lanes x ushort4 = 256B) per edge, 2 edges in flight.
__global__ void __launch_bounds__(256) k_agg1(const ushort* __restrict__ xb, const int* __restrict__ csr,
                                              const int* __restrict__ row_ptr, const float* __restrict__ inv_deg,
                                              ushort* __restrict__ agg1b, int N) {
  int n = blockIdx.x * 4 + (threadIdx.x >> 6);
  if (n >= N) return;
  int lane = threadIdx.x & 63, half = lane >> 5, p = lane & 31;
  int s = row_ptr[n], e = row_ptr[n + 1];
  float ax = 0.f, ay = 0.f, az = 0.f, aw = 0.f;
  for (int i = s + half; i < e; i += 2) {
    int sn = csr[i];
    ushort4 v = *(const ushort4*)(xb + (size_t)sn * 128 + p * 4);
    ax += bf2f(v.x); ay += bf2f(v.y); az += bf2f(v.z); aw += bf2f(v.w);
  }
  ax += __shfl_xor(ax, 32); ay += __shfl_xor(ay, 32);
  az += __shfl_xor(az, 32); aw += __shfl_xor(aw, 32);
  if (half == 0) {
    float inv = inv_deg[n];
    ushort4 o;
    o.x = f2bf(ax * inv); o.y = f2bf(ay * inv);
    o.z = f2bf(az * inv); o.w = f2bf(aw * inv);
    *(ushort4*)(agg1b + (size_t)n * 128 + p * 4) = o;
  }
}

// Fused MFMA MLP: g = relu(agg1 @ W1T + b1) @ W2T, bf16 in/out, fp32 accum.
// Block: 256 threads (4 waves), 64-node M-tile.
// Phase1: each wave computes h[64][64-col-slice]; Phase2: each wave computes g[16-row-slice][64].
__global__ void __launch_bounds__(256) k_mlp(const ushort* __restrict__ agg1b, const bf16x8* __restrict__ w1f,
                                             const float* __restrict__ b1, const bf16x8* __restrict__ w2f,
                                             ushort* __restrict__ gb, int N) {
  __shared__ __align__(16) ushort sm[16896];  // 33792 B
  ushort* aT = sm;   // phase1: [64][136]  (272B row stride -> 2-way bank alias, free)
  ushort* hT = sm;   // phase2: [64][264]  (528B row stride -> 2-way)
  const int t = threadIdx.x;
  const int n0 = blockIdx.x * 64;

  // Stage A tile: 64 rows x 128 bf16 = 1024 x bf16x8 chunks, 16B loads, coalesced.
#pragma unroll
  for (int i = 0; i < 4; ++i) {
    int idx = i * 256 + t;            // 1024 x 16B
    int row = idx >> 4, c8 = idx & 15;
    int rr = n0 + row; if (rr >= N) rr = N - 1;
    bf16x8 v = *(const bf16x8*)(agg1b + (size_t)rr * 128 + c8 * 8);
    *(bf16x8*)(aT + row * 136 + c8 * 8) = v;
  }
  __syncthreads();

  const int w = t >> 6, l = t & 63;
  const int lm = l & 15, lq = l >> 4;

  f32x4 acc[4][4];
#pragma unroll
  for (int mt = 0; mt < 4; ++mt)
#pragma unroll
    for (int nt = 0; nt < 4; ++nt) acc[mt][nt] = (f32x4)(0.f);

#pragma unroll
  for (int kt = 0; kt < 4; ++kt) {
    bf16x8 b[4], a[4];
#pragma unroll
    for (int nt = 0; nt < 4; ++nt)
      b[nt] = w1f[((w * 4 + nt) * 4 + kt) * 64 + l];
#pragma unroll
    for (int mt = 0; mt < 4; ++mt)
      a[mt] = *(const bf16x8*)(aT + (mt * 16 + lm) * 136 + kt * 32 + lq * 8);
#pragma unroll
    for (int mt = 0; mt < 4; ++mt)
#pragma unroll
      for (int nt = 0; nt < 4; ++nt)
        acc[mt][nt] = __builtin_amdgcn_mfma_f32_16x16x32_bf16(a[mt], b[nt], acc[mt][nt], 0, 0, 0);
  }
  __syncthreads();  // all aT reads done before hT overwrites

  // Epilogue 1: h = relu(acc + b1) -> hT (bf16). C/D layout: col=lane&15, row=lq*4+reg.
#pragma unroll
  for (int nt = 0; nt < 4; ++nt) {
    int col = w * 64 + nt * 16 + lm;
    float bb = b1[col];
#pragma unroll
    for (int mt = 0; mt < 4; ++mt)
#pragma unroll
      for (int r = 0; r < 4; ++r) {
        int row = mt * 16 + lq * 4 + r;
        float hv = acc[mt][nt][r] + bb;
        hT[row * 264 + col] = f2bf(fmaxf(hv, 0.f));
      }
  }
  __syncthreads();

  // Phase 2: g[64][64] = hT @ W2T. Wave w: rows [16w,16w+16), K=256.
  f32x4 acc2[4];
#pragma unroll
  for (int ot = 0; ot < 4; ++ot) acc2[ot] = (f32x4)(0.f);
#pragma unroll
  for (int kt = 0; kt < 8; ++kt) {
    bf16x8 a2 = *(const bf16x8*)(hT + (w * 16 + lm) * 264 + kt * 32 + lq * 8);
#pragma unroll
    for (int ot = 0; ot < 4; ++ot) {
      bf16x8 bf = w2f[(ot * 8 + kt) * 64 + l];
      acc2[ot] = __builtin_amdgcn_mfma_f32_16x16x32_bf16(a2, bf, acc2[ot], 0, 0, 0);
    }
  }
  // Epilogue 2: write g bf16.
#pragma unroll
  for (int ot = 0; ot < 4; ++ot)
#pragma unroll
    for (int r = 0; r < 4; ++r) {
      int row = n0 + w * 16 + lq * 4 + r;
      if (row < N) gb[(size_t)row * 64 + ot * 16 + lm] = f2bf(acc2[ot][r]);
    }
}

// agg2 + b2 + log_softmax fused. Wave per node; quarter-wave (16 lanes x ushort4 = 128B) per edge.
__global__ void __launch_bounds__(256) k_agg2(const ushort* __restrict__ gb, const int* __restrict__ csr,
                                              const int* __restrict__ row_ptr, const float* __restrict__ inv_deg,
                                              const float* __restrict__ b2, float* __restrict__ out, int N) {
  int n = blockIdx.x * 4 + (threadIdx.x >> 6);
  if (n >= N) return;
  int lane = threadIdx.x & 63;
  int q = lane >> 4, p = lane & 15;
  int s = row_ptr[n], e = row_ptr[n + 1];
  float ax = 0.f, ay = 0.f, az = 0.f, aw = 0.f;
  for (int i = s + q; i < e; i += 4) {
    int sn = csr[i];
    ushort4 v = *(const ushort4*)(gb + (size_t)sn * 64 + p * 4);
    ax += bf2f(v.x); ay += bf2f(v.y); az += bf2f(v.z); aw += bf2f(v.w);
  }
  ax += __shfl_xor(ax, 16); ay += __shfl_xor(ay, 16);
  az += __shfl_xor(az, 16); aw += __shfl_xor(aw, 16);
  ax += __shfl_xor(ax, 32); ay += __shfl_xor(ay, 32);
  az += __shfl_xor(az, 32); aw += __shfl_xor(aw, 32);
  float inv = inv_deg[n];
  float4 b = *(const float4*)(b2 + p * 4);
  float4 v;
  v.x = ax * inv + b.x;
  v.y = ay * inv + b.y;
  v.z = az * inv + b.z;
  v.w = aw * inv + b.w;
  float mx = fmaxf(fmaxf(v.x, v.y), fmaxf(v.z, v.w));
#pragma unroll
  for (int off = 1; off <= 8; off <<= 1) mx = fmaxf(mx, __shfl_xor(mx, off));
  float se = expf(v.x - mx) + expf(v.y - mx) + expf(v.z - mx) + expf(v.w - mx);
#pragma unroll
  for (int off = 1; off <= 8; off <<= 1) se += __shfl_xor(se, off);
  float lse = mx + logf(se);
  v.x -= lse; v.y -= lse; v.z -= lse; v.w -= lse;
  if (q == 0) *(float4*)(out + (size_t)n * 64 + p * 4) = v;
}

extern "C" void kernel_launch(void* const* d_in, const int* in_sizes, int n_in,
                              void* d_out, int out_size, void* d_ws, size_t ws_size,
                              hipStream_t stream) {
  const float* x  = (const float*)d_in[0];
  const int*   ei = (const int*)d_in[1];
  const float* W1 = (const float*)d_in[2];
  const float* b1 = (const float*)d_in[3];
  const float* W2 = (const float*)d_in[4];
  const float* b2 = (const float*)d_in[5];
  float* out = (float*)d_out;
  const int N = in_sizes[0] / 128;  // 100000
  const int E = in_sizes[1] / 2;    // 1600000

  char* base = (char*)d_ws;
  size_t off = 0;
  auto alloc = [&](size_t bytes) -> char* {
    char* p = base + off;
    off += (bytes + 255) & ~(size_t)255;
    return p;
  };
  int*    flag    = (int*)alloc(4);
  int*    deg     = (int*)alloc((size_t)N * 4);
  int*    part    = (int*)alloc(1024);
  int*    row_ptr = (int*)alloc((size_t)(N + 1) * 4);
  int*    rp_mut  = (int*)alloc((size_t)N * 4);
  float*  inv_deg = (float*)alloc((size_t)N * 4);
  int*    csr     = (int*)alloc((size_t)E * 4);
  ushort* xb      = (ushort*)alloc((size_t)N * 128 * 2);
  ushort* W1f     = (ushort*)alloc((size_t)32768 * 2);
  ushort* W2f     = (ushort*)alloc((size_t)16384 * 2);
  ushort* agg1b   = (ushort*)alloc((size_t)N * 128 * 2);
  ushort* gb      = (ushort*)alloc((size_t)N * 64 * 2);
  (void)ws_size; (void)n_in; (void)out_size;

  hipMemsetAsync(deg, 0, (size_t)N * 4, stream);
  k_detect<<<1, 64, 0, stream>>>(ei, flag);
  k_prep_x<<<(N * 128 / 4 + 255) / 256, 256, 0, stream>>>((const float4*)x, (ushort4*)xb, N * 128 / 4);
  k_prep_w<<<192, 256, 0, stream>>>(W1, W2, W1f, W2f);
  k_hist<<<(E + 255) / 256, 256, 0, stream>>>(ei, flag, deg, E);
  int NB = (N + 1023) / 1024;  // 98
  k_partial<<<NB, 256, 0, stream>>>(deg, part, N);
  k_scan_part<<<1, 128, 0, stream>>>(part, row_ptr, NB, N);
  k_scan_final<<<NB, 256, 0, stream>>>(deg, part, row_ptr, rp_mut, inv_deg, N);
  k_fill<<<(E + 255) / 256, 256, 0, stream>>>(ei, flag, rp_mut, csr, E);
  k_agg1<<<(N + 3) / 4, 256, 0, stream>>>(xb, csr, row_ptr, inv_deg, agg1b, N);
  k_mlp<<<(N + 63) / 64, 256, 0, stream>>>(agg1b, (const bf16x8*)W1f, b1, (const bf16x8*)W2f, gb, N);
  k_agg2<<<(N + 3) / 4, 256, 0, stream>>>(gb, csr, row_ptr, inv_deg, b2, out, N);
}

// Round 4
// 353.764 us; speedup vs baseline: 1.9191x; 1.4058x over previous
//
#include <hip/hip_runtime.h>

// GraphSAGE 2-layer inference.
// Pipeline: detect edge dtype -> prep (x->bf16, W1/W2 -> MFMA-fragment-ordered bf16)
//  -> bucketed CSR build: bhist/bscan -> bin (counting-sort edges into 1024-node
//     buckets, coalesced 4B packed writes) -> bcsr (per-bucket LDS hist/scan ->
//     row_ptr/inv_deg + L2-local csr scatter)
//  -> agg1 = A_mean * x_bf16        (gather, half-wave ushort4 lanes, fp32 accum, bf16 out)
//  -> fused MLP (bf16 MFMA): g = relu(agg1 @ W1T + b1) @ W2T  -> bf16
//  -> agg2 = A_mean * g + b2 -> log_softmax (gather bf16, fp32 out)
// Linear-commutes-with-mean: layer2 projects 256->64 BEFORE aggregation (4x less gather).

typedef __attribute__((ext_vector_type(8))) short bf16x8;
typedef __attribute__((ext_vector_type(4))) float f32x4;

#define BSHIFT 10            // 1024 nodes per bucket
#define BMASK  1023
#define SRCMASK 0x1FFFF      // 17 bits for src (N < 131072)
#define TBIN   4096          // edges per k_bin tile

__device__ inline ushort f2bf(float f) {
  union { float f; unsigned u; } c; c.f = f;
  unsigned r = (c.u + 0x7fffu + ((c.u >> 16) & 1u)) >> 16;
  return (ushort)r;
}
__device__ inline float bf2f(ushort u) {
  union { unsigned u; float f; } c; c.u = ((unsigned)u) << 16;
  return c.f;
}

__global__ void __launch_bounds__(64) k_detect(const int* __restrict__ ei, int* __restrict__ flag) {
  // int64 edge data (values < 2^31) => every odd int32 word is 0.
  int t = threadIdx.x;
  int v = ei[2 * t + 1];
  unsigned long long m = __ballot(v != 0);
  if (t == 0) *flag = (m == 0ull) ? 1 : 0;
}

// x fp32 -> bf16
__global__ void __launch_bounds__(256) k_prep_x(const float4* __restrict__ x4, ushort4* __restrict__ xb4, int total4) {
  int i = blockIdx.x * 256 + threadIdx.x;
  if (i >= total4) return;
  float4 v = x4[i];
  ushort4 o;
  o.x = f2bf(v.x); o.y = f2bf(v.y); o.z = f2bf(v.z); o.w = f2bf(v.w);
  xb4[i] = o;
}

// W1[256][128], W2[64][256] -> bf16 MFMA B-fragment order.
// 16x16x32 bf16 B-frag: lane l holds B[k = kt*32 + (l>>4)*8 + e][n = nt*16 + (l&15)], e=0..7.
__global__ void __launch_bounds__(256) k_prep_w(const float* __restrict__ W1, const float* __restrict__ W2,
                                                ushort* __restrict__ W1f, ushort* __restrict__ W2f) {
  int idx = blockIdx.x * 256 + threadIdx.x;
  if (idx < 32768) {
    int jt = idx >> 11, rem = idx & 2047;
    int kt = rem >> 9, rem2 = rem & 511;
    int l = rem2 >> 3, e = rem2 & 7;
    int k = kt * 32 + (l >> 4) * 8 + e;
    int j = jt * 16 + (l & 15);
    W1f[idx] = f2bf(W1[j * 128 + k]);
  } else {
    int i2 = idx - 32768;
    if (i2 < 16384) {
      int ot = i2 >> 12, rem = i2 & 4095;
      int kt = rem >> 9;
      int l = (rem >> 3) & 63, e = rem & 7;
      int k = kt * 32 + (l >> 4) * 8 + e;
      int o = ot * 16 + (l & 15);
      W2f[i2] = f2bf(W2[o * 256 + k]);
    }
  }
}

// Per-bucket edge counts (LDS-aggregated).
__global__ void __launch_bounds__(256) k_bhist(const int* __restrict__ ei, const int* __restrict__ flag,
                                               int* __restrict__ bcnt, int E, int NB) {
  __shared__ int h[128];
  int t = threadIdx.x;
  if (t < 128) h[t] = 0;
  __syncthreads();
  bool f64 = (*flag != 0);
  int stride = gridDim.x * 256;
  for (int e = blockIdx.x * 256 + t; e < E; e += stride) {
    int d;
    if (f64) d = (int)((const long long*)ei)[(size_t)E + e];
    else     d = ei[(size_t)E + e];
    atomicAdd(&h[d >> BSHIFT], 1);
  }
  __syncthreads();
  if (t < NB && h[t]) atomicAdd(&bcnt[t], h[t]);
}

// Scan bucket counts -> bucket_base[NB+1]; init bin cursors; row_ptr[N] = E.
__global__ void __launch_bounds__(128) k_bscan(const int* __restrict__ bcnt, int* __restrict__ bbase,
                                               int* __restrict__ bcur, int* __restrict__ row_ptr,
                                               int NB, int N, int E) {
  __shared__ int s[128];
  int t = threadIdx.x;
  int v = (t < NB) ? bcnt[t] : 0;
  s[t] = v;
  __syncthreads();
  for (int o = 1; o < 128; o <<= 1) {
    int u = (t >= o) ? s[t - o] : 0;
    __syncthreads();
    s[t] += u;
    __syncthreads();
  }
  if (t < NB) {
    int base = s[t] - v;
    bbase[t] = base;
    bcur[t] = base;
  }
  if (t == 0) {
    bbase[NB] = E;
    row_ptr[N] = E;
  }
}

// Counting-sort edges into bucket-segmented packed array. Per 4096-edge tile:
// LDS hist -> scan -> global segment reservation -> LDS place -> coalesced flush.
__global__ void __launch_bounds__(256) k_bin(const int* __restrict__ ei, const int* __restrict__ flag,
                                             int* __restrict__ bcur, int* __restrict__ gpair, int E, int NB) {
  __shared__ int hist[128], base[128], segb[128], cur[128], scanb[128];
  __shared__ int ent[TBIN];
  __shared__ int gdx[TBIN];
  int t = threadIdx.x;
  int e0 = blockIdx.x * TBIN;
  int cnt = E - e0; if (cnt > TBIN) cnt = TBIN;
  if (t < 128) hist[t] = 0;
  __syncthreads();
  bool f64 = (*flag != 0);
  int ment[16], mbk[16];
#pragma unroll
  for (int i = 0; i < 16; ++i) {
    int idx = t + i * 256;
    mbk[i] = -1;
    if (idx < cnt) {
      int e = e0 + idx;
      int s, d;
      if (f64) {
        const long long* p = (const long long*)ei;
        s = (int)p[e];
        d = (int)p[(size_t)E + e];
      } else {
        s = ei[e];
        d = ei[(size_t)E + e];
      }
      int b = d >> BSHIFT;
      mbk[i] = b;
      ment[i] = ((d & BMASK) << 17) | s;
      atomicAdd(&hist[b], 1);
    }
  }
  __syncthreads();
  // exclusive scan of hist[0..127]
  if (t < 128) scanb[t] = hist[t];
  __syncthreads();
  for (int o = 1; o < 128; o <<= 1) {
    int u = 0;
    if (t < 128 && t >= o) u = scanb[t - o];
    __syncthreads();
    if (t < 128) scanb[t] += u;
    __syncthreads();
  }
  if (t < 128) {
    int b0 = scanb[t] - hist[t];
    base[t] = b0;
    cur[t] = b0;
    segb[t] = (t < NB && hist[t] > 0) ? atomicAdd(&bcur[t], hist[t]) : 0;
  }
  __syncthreads();
#pragma unroll
  for (int i = 0; i < 16; ++i) {
    int b = mbk[i];
    if (b >= 0) {
      int pos = atomicAdd(&cur[b], 1);
      ent[pos] = ment[i];
      gdx[pos] = segb[b] + (pos - base[b]);
    }
  }
  __syncthreads();
  for (int i = t; i < cnt; i += 256) gpair[gdx[i]] = ent[i];
}

// Per-bucket CSR: LDS hist(1024) -> scan -> row_ptr/inv_deg; scatter csr in L2-local window.
__global__ void __launch_bounds__(1024) k_bcsr(const int* __restrict__ gpair, const int* __restrict__ bbase,
                                               int* __restrict__ row_ptr, float* __restrict__ inv_deg,
                                               int* __restrict__ csr, int N) {
  __shared__ int hist[1024], pre[1024], cur[1024];
  int b = blockIdx.x, t = threadIdx.x;
  int start = bbase[b], end = bbase[b + 1];
  hist[t] = 0;
  __syncthreads();
  for (int i = start + t; i < end; i += 1024) {
    int e = gpair[i];
    atomicAdd(&hist[e >> 17], 1);
  }
  __syncthreads();
  pre[t] = hist[t];
  __syncthreads();
  for (int o = 1; o < 1024; o <<= 1) {
    int u = (t >= o) ? pre[t - o] : 0;
    __syncthreads();
    pre[t] += u;
    __syncthreads();
  }
  int gbase = start + pre[t] - hist[t];
  int n = (b << BSHIFT) + t;
  if (n < N) {
    row_ptr[n] = gbase;
    inv_deg[n] = 1.0f / (float)(hist[t] > 0 ? hist[t] : 1);
  }
  cur[t] = gbase;
  __syncthreads();
  for (int i = start + t; i < end; i += 1024) {
    int e = gpair[i];
    int pos = atomicAdd(&cur[e >> 17], 1);
    csr[pos] = e & SRCMASK;
  }
}

// agg1b[n] = bf16( inv_deg[n] * sum_{e in row n} xb[csr[e]] )
// wave per node; half-wave (32 lanes x ushort4 = 256B) per edge, 2 edges in flight.
__global__ void __launch_bounds__(256) k_agg1(const ushort* __restrict__ xb, const int* __restrict__ csr,
                                              const int* __restrict__ row_ptr, const float* __restrict__ inv_deg,
                                              ushort* __restrict__ agg1b, int N) {
  int n = blockIdx.x * 4 + (threadIdx.x >> 6);
  if (n >= N) return;
  int lane = threadIdx.x & 63, half = lane >> 5, p = lane & 31;
  int s = row_ptr[n], e = row_ptr[n + 1];
  float ax = 0.f, ay = 0.f, az = 0.f, aw = 0.f;
  for (int i = s + half; i < e; i += 2) {
    int sn = csr[i];
    ushort4 v = *(const ushort4*)(xb + (size_t)sn * 128 + p * 4);
    ax += bf2f(v.x); ay += bf2f(v.y); az += bf2f(v.z); aw += bf2f(v.w);
  }
  ax += __shfl_xor(ax, 32); ay += __shfl_xor(ay, 32);
  az += __shfl_xor(az, 32); aw += __shfl_xor(aw, 32);
  if (half == 0) {
    float inv = inv_deg[n];
    ushort4 o;
    o.x = f2bf(ax * inv); o.y = f2bf(ay * inv);
    o.z = f2bf(az * inv); o.w = f2bf(aw * inv);
    *(ushort4*)(agg1b + (size_t)n * 128 + p * 4) = o;
  }
}

// Fused MFMA MLP: g = relu(agg1 @ W1T + b1) @ W2T, bf16 in/out, fp32 accum.
__global__ void __launch_bounds__(256) k_mlp(const ushort* __restrict__ agg1b, const bf16x8* __restrict__ w1f,
                                             const float* __restrict__ b1, const bf16x8* __restrict__ w2f,
                                             ushort* __restrict__ gb, int N) {
  __shared__ __align__(16) ushort sm[16896];  // 33792 B
  ushort* aT = sm;   // phase1: [64][136]  (272B row stride -> 2-way bank alias, free)
  ushort* hT = sm;   // phase2: [64][264]  (528B row stride -> 2-way)
  const int t = threadIdx.x;
  const int n0 = blockIdx.x * 64;

  // Stage A tile: 64 rows x 128 bf16 = 1024 x bf16x8 chunks, 16B loads, coalesced.
#pragma unroll
  for (int i = 0; i < 4; ++i) {
    int idx = i * 256 + t;            // 1024 x 16B
    int row = idx >> 4, c8 = idx & 15;
    int rr = n0 + row; if (rr >= N) rr = N - 1;
    bf16x8 v = *(const bf16x8*)(agg1b + (size_t)rr * 128 + c8 * 8);
    *(bf16x8*)(aT + row * 136 + c8 * 8) = v;
  }
  __syncthreads();

  const int w = t >> 6, l = t & 63;
  const int lm = l & 15, lq = l >> 4;

  f32x4 acc[4][4];
#pragma unroll
  for (int mt = 0; mt < 4; ++mt)
#pragma unroll
    for (int nt = 0; nt < 4; ++nt) acc[mt][nt] = (f32x4)(0.f);

#pragma unroll
  for (int kt = 0; kt < 4; ++kt) {
    bf16x8 b[4], a[4];
#pragma unroll
    for (int nt = 0; nt < 4; ++nt)
      b[nt] = w1f[((w * 4 + nt) * 4 + kt) * 64 + l];
#pragma unroll
    for (int mt = 0; mt < 4; ++mt)
      a[mt] = *(const bf16x8*)(aT + (mt * 16 + lm) * 136 + kt * 32 + lq * 8);
#pragma unroll
    for (int mt = 0; mt < 4; ++mt)
#pragma unroll
      for (int nt = 0; nt < 4; ++nt)
        acc[mt][nt] = __builtin_amdgcn_mfma_f32_16x16x32_bf16(a[mt], b[nt], acc[mt][nt], 0, 0, 0);
  }
  __syncthreads();  // all aT reads done before hT overwrites

  // Epilogue 1: h = relu(acc + b1) -> hT (bf16). C/D layout: col=lane&15, row=lq*4+reg.
#pragma unroll
  for (int nt = 0; nt < 4; ++nt) {
    int col = w * 64 + nt * 16 + lm;
    float bb = b1[col];
#pragma unroll
    for (int mt = 0; mt < 4; ++mt)
#pragma unroll
      for (int r = 0; r < 4; ++r) {
        int row = mt * 16 + lq * 4 + r;
        float hv = acc[mt][nt][r] + bb;
        hT[row * 264 + col] = f2bf(fmaxf(hv, 0.f));
      }
  }
  __syncthreads();

  // Phase 2: g[64][64] = hT @ W2T. Wave w: rows [16w,16w+16), K=256.
  f32x4 acc2[4];
#pragma unroll
  for (int ot = 0; ot < 4; ++ot) acc2[ot] = (f32x4)(0.f);
#pragma unroll
  for (int kt = 0; kt < 8; ++kt) {
    bf16x8 a2 = *(const bf16x8*)(hT + (w * 16 + lm) * 264 + kt * 32 + lq * 8);
#pragma unroll
    for (int ot = 0; ot < 4; ++ot) {
      bf16x8 bf = w2f[(ot * 8 + kt) * 64 + l];
      acc2[ot] = __builtin_amdgcn_mfma_f32_16x16x32_bf16(a2, bf, acc2[ot], 0, 0, 0);
    }
  }
  // Epilogue 2: write g bf16.
#pragma unroll
  for (int ot = 0; ot < 4; ++ot)
#pragma unroll
    for (int r = 0; r < 4; ++r) {
      int row = n0 + w * 16 + lq * 4 + r;
      if (row < N) gb[(size_t)row * 64 + ot * 16 + lm] = f2bf(acc2[ot][r]);
    }
}

// agg2 + b2 + log_softmax fused. Wave per node; quarter-wave (16 lanes x ushort4 = 128B) per edge.
__global__ void __launch_bounds__(256) k_agg2(const ushort* __restrict__ gb, const int* __restrict__ csr,
                                              const int* __restrict__ row_ptr, const float* __restrict__ inv_deg,
                                              const float* __restrict__ b2, float* __restrict__ out, int N) {
  int n = blockIdx.x * 4 + (threadIdx.x >> 6);
  if (n >= N) return;
  int lane = threadIdx.x & 63;
  int q = lane >> 4, p = lane & 15;
  int s = row_ptr[n], e = row_ptr[n + 1];
  float ax = 0.f, ay = 0.f, az = 0.f, aw = 0.f;
  for (int i = s + q; i < e; i += 4) {
    int sn = csr[i];
    ushort4 v = *(const ushort4*)(gb + (size_t)sn * 64 + p * 4);
    ax += bf2f(v.x); ay += bf2f(v.y); az += bf2f(v.z); aw += bf2f(v.w);
  }
  ax += __shfl_xor(ax, 16); ay += __shfl_xor(ay, 16);
  az += __shfl_xor(az, 16); aw += __shfl_xor(aw, 16);
  ax += __shfl_xor(ax, 32); ay += __shfl_xor(ay, 32);
  az += __shfl_xor(az, 32); aw += __shfl_xor(aw, 32);
  float inv = inv_deg[n];
  float4 b = *(const float4*)(b2 + p * 4);
  float4 v;
  v.x = ax * inv + b.x;
  v.y = ay * inv + b.y;
  v.z = az * inv + b.z;
  v.w = aw * inv + b.w;
  float mx = fmaxf(fmaxf(v.x, v.y), fmaxf(v.z, v.w));
#pragma unroll
  for (int off = 1; off <= 8; off <<= 1) mx = fmaxf(mx, __shfl_xor(mx, off));
  float se = expf(v.x - mx) + expf(v.y - mx) + expf(v.z - mx) + expf(v.w - mx);
#pragma unroll
  for (int off = 1; off <= 8; off <<= 1) se += __shfl_xor(se, off);
  float lse = mx + logf(se);
  v.x -= lse; v.y -= lse; v.z -= lse; v.w -= lse;
  if (q == 0) *(float4*)(out + (size_t)n * 64 + p * 4) = v;
}

extern "C" void kernel_launch(void* const* d_in, const int* in_sizes, int n_in,
                              void* d_out, int out_size, void* d_ws, size_t ws_size,
                              hipStream_t stream) {
  const float* x  = (const float*)d_in[0];
  const int*   ei = (const int*)d_in[1];
  const float* W1 = (const float*)d_in[2];
  const float* b1 = (const float*)d_in[3];
  const float* W2 = (const float*)d_in[4];
  const float* b2 = (const float*)d_in[5];
  float* out = (float*)d_out;
  const int N = in_sizes[0] / 128;  // 100000
  const int E = in_sizes[1] / 2;    // 1600000
  const int NB = (N + BMASK) >> BSHIFT;  // 98

  char* base = (char*)d_ws;
  size_t off = 0;
  auto alloc = [&](size_t bytes) -> char* {
    char* p = base + off;
    off += (bytes + 255) & ~(size_t)255;
    return p;
  };
  int*    flag    = (int*)alloc(4);
  int*    bcnt    = (int*)alloc((size_t)NB * 4);
  int*    bbase   = (int*)alloc((size_t)(NB + 1) * 4);
  int*    bcur    = (int*)alloc((size_t)NB * 4);
  int*    gpair   = (int*)alloc((size_t)E * 4);
  int*    row_ptr = (int*)alloc((size_t)(N + 1) * 4);
  float*  inv_deg = (float*)alloc((size_t)N * 4);
  int*    csr     = (int*)alloc((size_t)E * 4);
  ushort* xb      = (ushort*)alloc((size_t)N * 128 * 2);
  ushort* W1f     = (ushort*)alloc((size_t)32768 * 2);
  ushort* W2f     = (ushort*)alloc((size_t)16384 * 2);
  ushort* agg1b   = (ushort*)alloc((size_t)N * 128 * 2);
  ushort* gb      = (ushort*)alloc((size_t)N * 64 * 2);
  (void)ws_size; (void)n_in; (void)out_size;

  hipMemsetAsync(bcnt, 0, (size_t)NB * 4, stream);
  k_detect<<<1, 64, 0, stream>>>(ei, flag);
  k_prep_x<<<(N * 128 / 4 + 255) / 256, 256, 0, stream>>>((const float4*)x, (ushort4*)xb, N * 128 / 4);
  k_prep_w<<<192, 256, 0, stream>>>(W1, W2, W1f, W2f);
  k_bhist<<<512, 256, 0, stream>>>(ei, flag, bcnt, E, NB);
  k_bscan<<<1, 128, 0, stream>>>(bcnt, bbase, bcur, row_ptr, NB, N, E);
  k_bin<<<(E + TBIN - 1) / TBIN, 256, 0, stream>>>(ei, flag, bcur, gpair, E, NB);
  k_bcsr<<<NB, 1024, 0, stream>>>(gpair, bbase, row_ptr, inv_deg, csr, N);
  k_agg1<<<(N + 3) / 4, 256, 0, stream>>>(xb, csr, row_ptr, inv_deg, agg1b, N);
  k_mlp<<<(N + 63) / 64, 256, 0, stream>>>(agg1b, (const bf16x8*)W1f, b1, (const bf16x8*)W2f, gb, N);
  k_agg2<<<(N + 3) / 4, 256, 0, stream>>>(gb, csr, row_ptr, inv_deg, b2, out, N);
}

// Round 5
// 320.126 us; speedup vs baseline: 2.1208x; 1.1051x over previous
//
#include <hip/hip_runtime.h>

// GraphSAGE 2-layer inference.
// Pipeline: detect edge dtype -> prep (x->bf16, W1/W2 -> MFMA-fragment-ordered bf16)
//  -> bucketed CSR build: bhist/bscan -> bin (counting-sort edges into 1024-node
//     buckets, coalesced 4B packed writes) -> bcsr (per-bucket LDS hist/scan ->
//     row_ptr/inv_deg + L2-local csr scatter)
//  -> agg1 = A_mean * x_bf16   (gather, half-wave ushort4, 4 chains -> 8 loads in flight)
//  -> fused MLP (bf16 MFMA): g = relu(agg1 @ W1T + b1) @ W2T  -> bf16
//  -> agg2 = A_mean * g + b2 -> log_softmax (gather bf16, 4x unrolled, fp32 out)
// Linear-commutes-with-mean: layer2 projects 256->64 BEFORE aggregation (4x less gather).

typedef __attribute__((ext_vector_type(8))) short bf16x8;
typedef __attribute__((ext_vector_type(4))) float f32x4;

#define BSHIFT 10            // 1024 nodes per bucket
#define BMASK  1023
#define SRCMASK 0x1FFFF      // 17 bits for src (N < 131072)
#define TBIN   4096          // edges per k_bin tile

__device__ inline ushort f2bf(float f) {
  union { float f; unsigned u; } c; c.f = f;
  unsigned r = (c.u + 0x7fffu + ((c.u >> 16) & 1u)) >> 16;
  return (ushort)r;
}
__device__ inline float bf2f(ushort u) {
  union { unsigned u; float f; } c; c.u = ((unsigned)u) << 16;
  return c.f;
}

__global__ void __launch_bounds__(64) k_detect(const int* __restrict__ ei, int* __restrict__ flag) {
  // int64 edge data (values < 2^31) => every odd int32 word is 0.
  int t = threadIdx.x;
  int v = ei[2 * t + 1];
  unsigned long long m = __ballot(v != 0);
  if (t == 0) *flag = (m == 0ull) ? 1 : 0;
}

// x fp32 -> bf16
__global__ void __launch_bounds__(256) k_prep_x(const float4* __restrict__ x4, ushort4* __restrict__ xb4, int total4) {
  int i = blockIdx.x * 256 + threadIdx.x;
  if (i >= total4) return;
  float4 v = x4[i];
  ushort4 o;
  o.x = f2bf(v.x); o.y = f2bf(v.y); o.z = f2bf(v.z); o.w = f2bf(v.w);
  xb4[i] = o;
}

// W1[256][128], W2[64][256] -> bf16 MFMA B-fragment order.
// 16x16x32 bf16 B-frag: lane l holds B[k = kt*32 + (l>>4)*8 + e][n = nt*16 + (l&15)], e=0..7.
__global__ void __launch_bounds__(256) k_prep_w(const float* __restrict__ W1, const float* __restrict__ W2,
                                                ushort* __restrict__ W1f, ushort* __restrict__ W2f) {
  int idx = blockIdx.x * 256 + threadIdx.x;
  if (idx < 32768) {
    int jt = idx >> 11, rem = idx & 2047;
    int kt = rem >> 9, rem2 = rem & 511;
    int l = rem2 >> 3, e = rem2 & 7;
    int k = kt * 32 + (l >> 4) * 8 + e;
    int j = jt * 16 + (l & 15);
    W1f[idx] = f2bf(W1[j * 128 + k]);
  } else {
    int i2 = idx - 32768;
    if (i2 < 16384) {
      int ot = i2 >> 12, rem = i2 & 4095;
      int kt = rem >> 9;
      int l = (rem >> 3) & 63, e = rem & 7;
      int k = kt * 32 + (l >> 4) * 8 + e;
      int o = ot * 16 + (l & 15);
      W2f[i2] = f2bf(W2[o * 256 + k]);
    }
  }
}

// Per-bucket edge counts (LDS-aggregated).
__global__ void __launch_bounds__(256) k_bhist(const int* __restrict__ ei, const int* __restrict__ flag,
                                               int* __restrict__ bcnt, int E, int NB) {
  __shared__ int h[128];
  int t = threadIdx.x;
  if (t < 128) h[t] = 0;
  __syncthreads();
  bool f64 = (*flag != 0);
  int stride = gridDim.x * 256;
  for (int e = blockIdx.x * 256 + t; e < E; e += stride) {
    int d;
    if (f64) d = (int)((const long long*)ei)[(size_t)E + e];
    else     d = ei[(size_t)E + e];
    atomicAdd(&h[d >> BSHIFT], 1);
  }
  __syncthreads();
  if (t < NB && h[t]) atomicAdd(&bcnt[t], h[t]);
}

// Scan bucket counts -> bucket_base[NB+1]; init bin cursors; row_ptr[N] = E.
__global__ void __launch_bounds__(128) k_bscan(const int* __restrict__ bcnt, int* __restrict__ bbase,
                                               int* __restrict__ bcur, int* __restrict__ row_ptr,
                                               int NB, int N, int E) {
  __shared__ int s[128];
  int t = threadIdx.x;
  int v = (t < NB) ? bcnt[t] : 0;
  s[t] = v;
  __syncthreads();
  for (int o = 1; o < 128; o <<= 1) {
    int u = (t >= o) ? s[t - o] : 0;
    __syncthreads();
    s[t] += u;
    __syncthreads();
  }
  if (t < NB) {
    int base = s[t] - v;
    bbase[t] = base;
    bcur[t] = base;
  }
  if (t == 0) {
    bbase[NB] = E;
    row_ptr[N] = E;
  }
}

// Counting-sort edges into bucket-segmented packed array. Per 4096-edge tile:
// LDS hist -> scan -> global segment reservation -> LDS place -> coalesced flush.
__global__ void __launch_bounds__(256) k_bin(const int* __restrict__ ei, const int* __restrict__ flag,
                                             int* __restrict__ bcur, int* __restrict__ gpair, int E, int NB) {
  __shared__ int hist[128], base[128], segb[128], cur[128], scanb[128];
  __shared__ int ent[TBIN];
  __shared__ int gdx[TBIN];
  int t = threadIdx.x;
  int e0 = blockIdx.x * TBIN;
  int cnt = E - e0; if (cnt > TBIN) cnt = TBIN;
  if (t < 128) hist[t] = 0;
  __syncthreads();
  bool f64 = (*flag != 0);
  int ment[16], mbk[16];
#pragma unroll
  for (int i = 0; i < 16; ++i) {
    int idx = t + i * 256;
    mbk[i] = -1;
    if (idx < cnt) {
      int e = e0 + idx;
      int s, d;
      if (f64) {
        const long long* p = (const long long*)ei;
        s = (int)p[e];
        d = (int)p[(size_t)E + e];
      } else {
        s = ei[e];
        d = ei[(size_t)E + e];
      }
      int b = d >> BSHIFT;
      mbk[i] = b;
      ment[i] = ((d & BMASK) << 17) | s;
      atomicAdd(&hist[b], 1);
    }
  }
  __syncthreads();
  // exclusive scan of hist[0..127]
  if (t < 128) scanb[t] = hist[t];
  __syncthreads();
  for (int o = 1; o < 128; o <<= 1) {
    int u = 0;
    if (t < 128 && t >= o) u = scanb[t - o];
    __syncthreads();
    if (t < 128) scanb[t] += u;
    __syncthreads();
  }
  if (t < 128) {
    int b0 = scanb[t] - hist[t];
    base[t] = b0;
    cur[t] = b0;
    segb[t] = (t < NB && hist[t] > 0) ? atomicAdd(&bcur[t], hist[t]) : 0;
  }
  __syncthreads();
#pragma unroll
  for (int i = 0; i < 16; ++i) {
    int b = mbk[i];
    if (b >= 0) {
      int pos = atomicAdd(&cur[b], 1);
      ent[pos] = ment[i];
      gdx[pos] = segb[b] + (pos - base[b]);
    }
  }
  __syncthreads();
  for (int i = t; i < cnt; i += 256) gpair[gdx[i]] = ent[i];
}

// Per-bucket CSR: LDS hist(1024) -> scan -> row_ptr/inv_deg; scatter csr in L2-local window.
__global__ void __launch_bounds__(1024) k_bcsr(const int* __restrict__ gpair, const int* __restrict__ bbase,
                                               int* __restrict__ row_ptr, float* __restrict__ inv_deg,
                                               int* __restrict__ csr, int N) {
  __shared__ int hist[1024], pre[1024], cur[1024];
  int b = blockIdx.x, t = threadIdx.x;
  int start = bbase[b], end = bbase[b + 1];
  hist[t] = 0;
  __syncthreads();
  for (int i = start + t; i < end; i += 1024) {
    int e = gpair[i];
    atomicAdd(&hist[e >> 17], 1);
  }
  __syncthreads();
  pre[t] = hist[t];
  __syncthreads();
  for (int o = 1; o < 1024; o <<= 1) {
    int u = (t >= o) ? pre[t - o] : 0;
    __syncthreads();
    pre[t] += u;
    __syncthreads();
  }
  int gbase = start + pre[t] - hist[t];
  int n = (b << BSHIFT) + t;
  if (n < N) {
    row_ptr[n] = gbase;
    inv_deg[n] = 1.0f / (float)(hist[t] > 0 ? hist[t] : 1);
  }
  cur[t] = gbase;
  __syncthreads();
  for (int i = start + t; i < end; i += 1024) {
    int e = gpair[i];
    int pos = atomicAdd(&cur[e >> 17], 1);
    csr[pos] = e & SRCMASK;
  }
}

// agg1b[n] = bf16( inv_deg[n] * sum_{e in row n} xb[csr[e]] )
// wave per node; half-wave (32 lanes x ushort4 = 256B) per edge.
// 4 independent accumulator chains per half-wave -> 8 loads in flight per wave (MLP boost).
__global__ void __launch_bounds__(256) k_agg1(const ushort* __restrict__ xb, const int* __restrict__ csr,
                                              const int* __restrict__ row_ptr, const float* __restrict__ inv_deg,
                                              ushort* __restrict__ agg1b, int N) {
  int n = blockIdx.x * 4 + (threadIdx.x >> 6);
  if (n >= N) return;
  int lane = threadIdx.x & 63, half = lane >> 5, p = lane & 31;
  int s = row_ptr[n], e = row_ptr[n + 1];
  float a0x = 0.f, a0y = 0.f, a0z = 0.f, a0w = 0.f;
  float a1x = 0.f, a1y = 0.f, a1z = 0.f, a1w = 0.f;
  float a2x = 0.f, a2y = 0.f, a2z = 0.f, a2w = 0.f;
  float a3x = 0.f, a3y = 0.f, a3z = 0.f, a3w = 0.f;
  int i = s + half;
  for (; i + 6 < e; i += 8) {
    int s0 = csr[i], s1 = csr[i + 2], s2 = csr[i + 4], s3 = csr[i + 6];
    ushort4 v0 = *(const ushort4*)(xb + (size_t)s0 * 128 + p * 4);
    ushort4 v1 = *(const ushort4*)(xb + (size_t)s1 * 128 + p * 4);
    ushort4 v2 = *(const ushort4*)(xb + (size_t)s2 * 128 + p * 4);
    ushort4 v3 = *(const ushort4*)(xb + (size_t)s3 * 128 + p * 4);
    a0x += bf2f(v0.x); a0y += bf2f(v0.y); a0z += bf2f(v0.z); a0w += bf2f(v0.w);
    a1x += bf2f(v1.x); a1y += bf2f(v1.y); a1z += bf2f(v1.z); a1w += bf2f(v1.w);
    a2x += bf2f(v2.x); a2y += bf2f(v2.y); a2z += bf2f(v2.z); a2w += bf2f(v2.w);
    a3x += bf2f(v3.x); a3y += bf2f(v3.y); a3z += bf2f(v3.z); a3w += bf2f(v3.w);
  }
  for (; i < e; i += 2) {
    int sn = csr[i];
    ushort4 v = *(const ushort4*)(xb + (size_t)sn * 128 + p * 4);
    a0x += bf2f(v.x); a0y += bf2f(v.y); a0z += bf2f(v.z); a0w += bf2f(v.w);
  }
  float ax = (a0x + a1x) + (a2x + a3x);
  float ay = (a0y + a1y) + (a2y + a3y);
  float az = (a0z + a1z) + (a2z + a3z);
  float aw = (a0w + a1w) + (a2w + a3w);
  ax += __shfl_xor(ax, 32); ay += __shfl_xor(ay, 32);
  az += __shfl_xor(az, 32); aw += __shfl_xor(aw, 32);
  if (half == 0) {
    float inv = inv_deg[n];
    ushort4 o;
    o.x = f2bf(ax * inv); o.y = f2bf(ay * inv);
    o.z = f2bf(az * inv); o.w = f2bf(aw * inv);
    *(ushort4*)(agg1b + (size_t)n * 128 + p * 4) = o;
  }
}

// Fused MFMA MLP: g = relu(agg1 @ W1T + b1) @ W2T, bf16 in/out, fp32 accum.
__global__ void __launch_bounds__(256) k_mlp(const ushort* __restrict__ agg1b, const bf16x8* __restrict__ w1f,
                                             const float* __restrict__ b1, const bf16x8* __restrict__ w2f,
                                             ushort* __restrict__ gb, int N) {
  __shared__ __align__(16) ushort sm[16896];  // 33792 B
  ushort* aT = sm;   // phase1: [64][136]  (272B row stride -> 2-way bank alias, free)
  ushort* hT = sm;   // phase2: [64][264]  (528B row stride -> 2-way)
  const int t = threadIdx.x;
  const int n0 = blockIdx.x * 64;

  // Stage A tile: 64 rows x 128 bf16 = 1024 x bf16x8 chunks, 16B loads, coalesced.
#pragma unroll
  for (int i = 0; i < 4; ++i) {
    int idx = i * 256 + t;            // 1024 x 16B
    int row = idx >> 4, c8 = idx & 15;
    int rr = n0 + row; if (rr >= N) rr = N - 1;
    bf16x8 v = *(const bf16x8*)(agg1b + (size_t)rr * 128 + c8 * 8);
    *(bf16x8*)(aT + row * 136 + c8 * 8) = v;
  }
  __syncthreads();

  const int w = t >> 6, l = t & 63;
  const int lm = l & 15, lq = l >> 4;

  f32x4 acc[4][4];
#pragma unroll
  for (int mt = 0; mt < 4; ++mt)
#pragma unroll
    for (int nt = 0; nt < 4; ++nt) acc[mt][nt] = (f32x4)(0.f);

#pragma unroll
  for (int kt = 0; kt < 4; ++kt) {
    bf16x8 b[4], a[4];
#pragma unroll
    for (int nt = 0; nt < 4; ++nt)
      b[nt] = w1f[((w * 4 + nt) * 4 + kt) * 64 + l];
#pragma unroll
    for (int mt = 0; mt < 4; ++mt)
      a[mt] = *(const bf16x8*)(aT + (mt * 16 + lm) * 136 + kt * 32 + lq * 8);
#pragma unroll
    for (int mt = 0; mt < 4; ++mt)
#pragma unroll
      for (int nt = 0; nt < 4; ++nt)
        acc[mt][nt] = __builtin_amdgcn_mfma_f32_16x16x32_bf16(a[mt], b[nt], acc[mt][nt], 0, 0, 0);
  }
  __syncthreads();  // all aT reads done before hT overwrites

  // Epilogue 1: h = relu(acc + b1) -> hT (bf16). C/D layout: col=lane&15, row=lq*4+reg.
#pragma unroll
  for (int nt = 0; nt < 4; ++nt) {
    int col = w * 64 + nt * 16 + lm;
    float bb = b1[col];
#pragma unroll
    for (int mt = 0; mt < 4; ++mt)
#pragma unroll
      for (int r = 0; r < 4; ++r) {
        int row = mt * 16 + lq * 4 + r;
        float hv = acc[mt][nt][r] + bb;
        hT[row * 264 + col] = f2bf(fmaxf(hv, 0.f));
      }
  }
  __syncthreads();

  // Phase 2: g[64][64] = hT @ W2T. Wave w: rows [16w,16w+16), K=256.
  f32x4 acc2[4];
#pragma unroll
  for (int ot = 0; ot < 4; ++ot) acc2[ot] = (f32x4)(0.f);
#pragma unroll
  for (int kt = 0; kt < 8; ++kt) {
    bf16x8 a2 = *(const bf16x8*)(hT + (w * 16 + lm) * 264 + kt * 32 + lq * 8);
#pragma unroll
    for (int ot = 0; ot < 4; ++ot) {
      bf16x8 bf = w2f[(ot * 8 + kt) * 64 + l];
      acc2[ot] = __builtin_amdgcn_mfma_f32_16x16x32_bf16(a2, bf, acc2[ot], 0, 0, 0);
    }
  }
  // Epilogue 2: write g bf16.
#pragma unroll
  for (int ot = 0; ot < 4; ++ot)
#pragma unroll
    for (int r = 0; r < 4; ++r) {
      int row = n0 + w * 16 + lq * 4 + r;
      if (row < N) gb[(size_t)row * 64 + ot * 16 + lm] = f2bf(acc2[ot][r]);
    }
}

// agg2 + b2 + log_softmax fused. Wave per node; quarter-wave (16 lanes x ushort4 = 128B) per edge.
// 4-way unroll -> 16 loads in flight per wave.
__global__ void __launch_bounds__(256) k_agg2(const ushort* __restrict__ gb, const int* __restrict__ csr,
                                              const int* __restrict__ row_ptr, const float* __restrict__ inv_deg,
                                              const float* __restrict__ b2, float* __restrict__ out, int N) {
  int n = blockIdx.x * 4 + (threadIdx.x >> 6);
  if (n >= N) return;
  int lane = threadIdx.x & 63;
  int q = lane >> 4, p = lane & 15;
  int s = row_ptr[n], e = row_ptr[n + 1];
  float a0x = 0.f, a0y = 0.f, a0z = 0.f, a0w = 0.f;
  float a1x = 0.f, a1y = 0.f, a1z = 0.f, a1w = 0.f;
  float a2x = 0.f, a2y = 0.f, a2z = 0.f, a2w = 0.f;
  float a3x = 0.f, a3y = 0.f, a3z = 0.f, a3w = 0.f;
  int i = s + q;
  for (; i + 12 < e; i += 16) {
    int s0 = csr[i], s1 = csr[i + 4], s2 = csr[i + 8], s3 = csr[i + 12];
    ushort4 v0 = *(const ushort4*)(gb + (size_t)s0 * 64 + p * 4);
    ushort4 v1 = *(const ushort4*)(gb + (size_t)s1 * 64 + p * 4);
    ushort4 v2 = *(const ushort4*)(gb + (size_t)s2 * 64 + p * 4);
    ushort4 v3 = *(const ushort4*)(gb + (size_t)s3 * 64 + p * 4);
    a0x += bf2f(v0.x); a0y += bf2f(v0.y); a0z += bf2f(v0.z); a0w += bf2f(v0.w);
    a1x += bf2f(v1.x); a1y += bf2f(v1.y); a1z += bf2f(v1.z); a1w += bf2f(v1.w);
    a2x += bf2f(v2.x); a2y += bf2f(v2.y); a2z += bf2f(v2.z); a2w += bf2f(v2.w);
    a3x += bf2f(v3.x); a3y += bf2f(v3.y); a3z += bf2f(v3.z); a3w += bf2f(v3.w);
  }
  for (; i < e; i += 4) {
    int sn = csr[i];
    ushort4 v = *(const ushort4*)(gb + (size_t)sn * 64 + p * 4);
    a0x += bf2f(v.x); a0y += bf2f(v.y); a0z += bf2f(v.z); a0w += bf2f(v.w);
  }
  float ax = (a0x + a1x) + (a2x + a3x);
  float ay = (a0y + a1y) + (a2y + a3y);
  float az = (a0z + a1z) + (a2z + a3z);
  float aw = (a0w + a1w) + (a2w + a3w);
  ax += __shfl_xor(ax, 16); ay += __shfl_xor(ay, 16);
  az += __shfl_xor(az, 16); aw += __shfl_xor(aw, 16);
  ax += __shfl_xor(ax, 32); ay += __shfl_xor(ay, 32);
  az += __shfl_xor(az, 32); aw += __shfl_xor(aw, 32);
  float inv = inv_deg[n];
  float4 b = *(const float4*)(b2 + p * 4);
  float4 v;
  v.x = ax * inv + b.x;
  v.y = ay * inv + b.y;
  v.z = az * inv + b.z;
  v.w = aw * inv + b.w;
  float mx = fmaxf(fmaxf(v.x, v.y), fmaxf(v.z, v.w));
#pragma unroll
  for (int off = 1; off <= 8; off <<= 1) mx = fmaxf(mx, __shfl_xor(mx, off));
  float se = expf(v.x - mx) + expf(v.y - mx) + expf(v.z - mx) + expf(v.w - mx);
#pragma unroll
  for (int off = 1; off <= 8; off <<= 1) se += __shfl_xor(se, off);
  float lse = mx + logf(se);
  v.x -= lse; v.y -= lse; v.z -= lse; v.w -= lse;
  if (q == 0) *(float4*)(out + (size_t)n * 64 + p * 4) = v;
}

extern "C" void kernel_launch(void* const* d_in, const int* in_sizes, int n_in,
                              void* d_out, int out_size, void* d_ws, size_t ws_size,
                              hipStream_t stream) {
  const float* x  = (const float*)d_in[0];
  const int*   ei = (const int*)d_in[1];
  const float* W1 = (const float*)d_in[2];
  const float* b1 = (const float*)d_in[3];
  const float* W2 = (const float*)d_in[4];
  const float* b2 = (const float*)d_in[5];
  float* out = (float*)d_out;
  const int N = in_sizes[0] / 128;  // 100000
  const int E = in_sizes[1] / 2;    // 1600000
  const int NB = (N + BMASK) >> BSHIFT;  // 98

  char* base = (char*)d_ws;
  size_t off = 0;
  auto alloc = [&](size_t bytes) -> char* {
    char* p = base + off;
    off += (bytes + 255) & ~(size_t)255;
    return p;
  };
  int*    flag    = (int*)alloc(4);
  int*    bcnt    = (int*)alloc((size_t)NB * 4);
  int*    bbase   = (int*)alloc((size_t)(NB + 1) * 4);
  int*    bcur    = (int*)alloc((size_t)NB * 4);
  int*    gpair   = (int*)alloc((size_t)E * 4);
  int*    row_ptr = (int*)alloc((size_t)(N + 1) * 4);
  float*  inv_deg = (float*)alloc((size_t)N * 4);
  int*    csr     = (int*)alloc((size_t)E * 4);
  ushort* xb      = (ushort*)alloc((size_t)N * 128 * 2);
  ushort* W1f     = (ushort*)alloc((size_t)32768 * 2);
  ushort* W2f     = (ushort*)alloc((size_t)16384 * 2);
  ushort* agg1b   = (ushort*)alloc((size_t)N * 128 * 2);
  ushort* gb      = (ushort*)alloc((size_t)N * 64 * 2);
  (void)ws_size; (void)n_in; (void)out_size;

  hipMemsetAsync(bcnt, 0, (size_t)NB * 4, stream);
  k_detect<<<1, 64, 0, stream>>>(ei, flag);
  k_prep_x<<<(N * 128 / 4 + 255) / 256, 256, 0, stream>>>((const float4*)x, (ushort4*)xb, N * 128 / 4);
  k_prep_w<<<192, 256, 0, stream>>>(W1, W2, W1f, W2f);
  k_bhist<<<512, 256, 0, stream>>>(ei, flag, bcnt, E, NB);
  k_bscan<<<1, 128, 0, stream>>>(bcnt, bbase, bcur, row_ptr, NB, N, E);
  k_bin<<<(E + TBIN - 1) / TBIN, 256, 0, stream>>>(ei, flag, bcur, gpair, E, NB);
  k_bcsr<<<NB, 1024, 0, stream>>>(gpair, bbase, row_ptr, inv_deg, csr, N);
  k_agg1<<<(N + 3) / 4, 256, 0, stream>>>(xb, csr, row_ptr, inv_deg, agg1b, N);
  k_mlp<<<(N + 63) / 64, 256, 0, stream>>>(agg1b, (const bf16x8*)W1f, b1, (const bf16x8*)W2f, gb, N);
  k_agg2<<<(N + 3) / 4, 256, 0, stream>>>(gb, csr, row_ptr, inv_deg, b2, out, N);
}

// Round 6
// 305.854 us; speedup vs baseline: 2.2197x; 1.0467x over previous
//
#include <hip/hip_runtime.h>

// GraphSAGE 2-layer inference.
// Pipeline: detect edge dtype -> prep (x->bf16, W1/W2 -> MFMA-fragment-ordered bf16)
//  -> bucketed CSR build: bhist/bscan -> bin (counting-sort edges into 1024-node
//     buckets, coalesced 4B packed writes) -> bcsr (per-bucket LDS hist/scan ->
//     row_ptr/inv_deg + L2-local csr scatter)
//  -> agg1 = A_mean * x_bf16   (gather, quarter-wave 16B lanes; csr indices loaded
//     once per 64-edge chunk + __shfl distribution -> no csr->gather vmcnt serialization)
//  -> fused MLP (bf16 MFMA): g = relu(agg1 @ W1T + b1) @ W2T  -> bf16
//  -> agg2 = A_mean * g + b2 -> log_softmax (same shfl-index gather, fp32 out)
// Linear-commutes-with-mean: layer2 projects 256->64 BEFORE aggregation (4x less gather).

typedef __attribute__((ext_vector_type(8))) short bf16x8;
typedef __attribute__((ext_vector_type(4))) float f32x4;

#define BSHIFT 10            // 1024 nodes per bucket
#define BMASK  1023
#define SRCMASK 0x1FFFF      // 17 bits for src (N < 131072)
#define TBIN   4096          // edges per k_bin tile

__device__ inline ushort f2bf(float f) {
  union { float f; unsigned u; } c; c.f = f;
  unsigned r = (c.u + 0x7fffu + ((c.u >> 16) & 1u)) >> 16;
  return (ushort)r;
}
__device__ inline float bf2f(ushort u) {
  union { unsigned u; float f; } c; c.u = ((unsigned)u) << 16;
  return c.f;
}

__global__ void __launch_bounds__(64) k_detect(const int* __restrict__ ei, int* __restrict__ flag) {
  // int64 edge data (values < 2^31) => every odd int32 word is 0.
  int t = threadIdx.x;
  int v = ei[2 * t + 1];
  unsigned long long m = __ballot(v != 0);
  if (t == 0) *flag = (m == 0ull) ? 1 : 0;
}

// x fp32 -> bf16
__global__ void __launch_bounds__(256) k_prep_x(const float4* __restrict__ x4, ushort4* __restrict__ xb4, int total4) {
  int i = blockIdx.x * 256 + threadIdx.x;
  if (i >= total4) return;
  float4 v = x4[i];
  ushort4 o;
  o.x = f2bf(v.x); o.y = f2bf(v.y); o.z = f2bf(v.z); o.w = f2bf(v.w);
  xb4[i] = o;
}

// W1[256][128], W2[64][256] -> bf16 MFMA B-fragment order.
// 16x16x32 bf16 B-frag: lane l holds B[k = kt*32 + (l>>4)*8 + e][n = nt*16 + (l&15)], e=0..7.
__global__ void __launch_bounds__(256) k_prep_w(const float* __restrict__ W1, const float* __restrict__ W2,
                                                ushort* __restrict__ W1f, ushort* __restrict__ W2f) {
  int idx = blockIdx.x * 256 + threadIdx.x;
  if (idx < 32768) {
    int jt = idx >> 11, rem = idx & 2047;
    int kt = rem >> 9, rem2 = rem & 511;
    int l = rem2 >> 3, e = rem2 & 7;
    int k = kt * 32 + (l >> 4) * 8 + e;
    int j = jt * 16 + (l & 15);
    W1f[idx] = f2bf(W1[j * 128 + k]);
  } else {
    int i2 = idx - 32768;
    if (i2 < 16384) {
      int ot = i2 >> 12, rem = i2 & 4095;
      int kt = rem >> 9;
      int l = (rem >> 3) & 63, e = rem & 7;
      int k = kt * 32 + (l >> 4) * 8 + e;
      int o = ot * 16 + (l & 15);
      W2f[i2] = f2bf(W2[o * 256 + k]);
    }
  }
}

// Per-bucket edge counts (LDS-aggregated).
__global__ void __launch_bounds__(256) k_bhist(const int* __restrict__ ei, const int* __restrict__ flag,
                                               int* __restrict__ bcnt, int E, int NB) {
  __shared__ int h[128];
  int t = threadIdx.x;
  if (t < 128) h[t] = 0;
  __syncthreads();
  bool f64 = (*flag != 0);
  int stride = gridDim.x * 256;
  for (int e = blockIdx.x * 256 + t; e < E; e += stride) {
    int d;
    if (f64) d = (int)((const long long*)ei)[(size_t)E + e];
    else     d = ei[(size_t)E + e];
    atomicAdd(&h[d >> BSHIFT], 1);
  }
  __syncthreads();
  if (t < NB && h[t]) atomicAdd(&bcnt[t], h[t]);
}

// Scan bucket counts -> bucket_base[NB+1]; init bin cursors; row_ptr[N] = E.
__global__ void __launch_bounds__(128) k_bscan(const int* __restrict__ bcnt, int* __restrict__ bbase,
                                               int* __restrict__ bcur, int* __restrict__ row_ptr,
                                               int NB, int N, int E) {
  __shared__ int s[128];
  int t = threadIdx.x;
  int v = (t < NB) ? bcnt[t] : 0;
  s[t] = v;
  __syncthreads();
  for (int o = 1; o < 128; o <<= 1) {
    int u = (t >= o) ? s[t - o] : 0;
    __syncthreads();
    s[t] += u;
    __syncthreads();
  }
  if (t < NB) {
    int base = s[t] - v;
    bbase[t] = base;
    bcur[t] = base;
  }
  if (t == 0) {
    bbase[NB] = E;
    row_ptr[N] = E;
  }
}

// Counting-sort edges into bucket-segmented packed array. Per 4096-edge tile:
// LDS hist -> scan -> global segment reservation -> LDS place -> coalesced flush.
__global__ void __launch_bounds__(256) k_bin(const int* __restrict__ ei, const int* __restrict__ flag,
                                             int* __restrict__ bcur, int* __restrict__ gpair, int E, int NB) {
  __shared__ int hist[128], base[128], segb[128], cur[128], scanb[128];
  __shared__ int ent[TBIN];
  __shared__ int gdx[TBIN];
  int t = threadIdx.x;
  int e0 = blockIdx.x * TBIN;
  int cnt = E - e0; if (cnt > TBIN) cnt = TBIN;
  if (t < 128) hist[t] = 0;
  __syncthreads();
  bool f64 = (*flag != 0);
  int ment[16], mbk[16];
#pragma unroll
  for (int i = 0; i < 16; ++i) {
    int idx = t + i * 256;
    mbk[i] = -1;
    if (idx < cnt) {
      int e = e0 + idx;
      int s, d;
      if (f64) {
        const long long* p = (const long long*)ei;
        s = (int)p[e];
        d = (int)p[(size_t)E + e];
      } else {
        s = ei[e];
        d = ei[(size_t)E + e];
      }
      int b = d >> BSHIFT;
      mbk[i] = b;
      ment[i] = ((d & BMASK) << 17) | s;
      atomicAdd(&hist[b], 1);
    }
  }
  __syncthreads();
  // exclusive scan of hist[0..127]
  if (t < 128) scanb[t] = hist[t];
  __syncthreads();
  for (int o = 1; o < 128; o <<= 1) {
    int u = 0;
    if (t < 128 && t >= o) u = scanb[t - o];
    __syncthreads();
    if (t < 128) scanb[t] += u;
    __syncthreads();
  }
  if (t < 128) {
    int b0 = scanb[t] - hist[t];
    base[t] = b0;
    cur[t] = b0;
    segb[t] = (t < NB && hist[t] > 0) ? atomicAdd(&bcur[t], hist[t]) : 0;
  }
  __syncthreads();
#pragma unroll
  for (int i = 0; i < 16; ++i) {
    int b = mbk[i];
    if (b >= 0) {
      int pos = atomicAdd(&cur[b], 1);
      ent[pos] = ment[i];
      gdx[pos] = segb[b] + (pos - base[b]);
    }
  }
  __syncthreads();
  for (int i = t; i < cnt; i += 256) gpair[gdx[i]] = ent[i];
}

// Per-bucket CSR: LDS hist(1024) -> scan -> row_ptr/inv_deg; scatter csr in L2-local window.
__global__ void __launch_bounds__(1024) k_bcsr(const int* __restrict__ gpair, const int* __restrict__ bbase,
                                               int* __restrict__ row_ptr, float* __restrict__ inv_deg,
                                               int* __restrict__ csr, int N) {
  __shared__ int hist[1024], pre[1024], cur[1024];
  int b = blockIdx.x, t = threadIdx.x;
  int start = bbase[b], end = bbase[b + 1];
  hist[t] = 0;
  __syncthreads();
  for (int i = start + t; i < end; i += 1024) {
    int e = gpair[i];
    atomicAdd(&hist[e >> 17], 1);
  }
  __syncthreads();
  pre[t] = hist[t];
  __syncthreads();
  for (int o = 1; o < 1024; o <<= 1) {
    int u = (t >= o) ? pre[t - o] : 0;
    __syncthreads();
    pre[t] += u;
    __syncthreads();
  }
  int gbase = start + pre[t] - hist[t];
  int n = (b << BSHIFT) + t;
  if (n < N) {
    row_ptr[n] = gbase;
    inv_deg[n] = 1.0f / (float)(hist[t] > 0 ? hist[t] : 1);
  }
  cur[t] = gbase;
  __syncthreads();
  for (int i = start + t; i < end; i += 1024) {
    int e = gpair[i];
    int pos = atomicAdd(&cur[e >> 17], 1);
    csr[pos] = e & SRCMASK;
  }
}

// agg1b[n] = bf16( inv_deg[n] * sum_{e in row n} xb[csr[e]] )
// Wave per node. Quarter-wave (16 lanes) x 16B = 256B per edge, 4 edges/instruction.
// csr indices loaded ONCE per 64-edge chunk (coalesced full-wave load) and distributed
// via __shfl (ds_bpermute, lgkm pipe) -> gather stream has no vmcnt-ordering stalls.
__global__ void __launch_bounds__(256) k_agg1(const ushort* __restrict__ xb, const int* __restrict__ csr,
                                              const int* __restrict__ row_ptr, const float* __restrict__ inv_deg,
                                              ushort* __restrict__ agg1b, int N) {
  int n = blockIdx.x * 4 + (threadIdx.x >> 6);
  if (n >= N) return;
  int lane = threadIdx.x & 63;
  int q = lane >> 4, p = lane & 15;
  int s = row_ptr[n], e = row_ptr[n + 1];
  float acc[4][8];
#pragma unroll
  for (int c = 0; c < 4; ++c)
#pragma unroll
    for (int k = 0; k < 8; ++k) acc[c][k] = 0.f;

  for (int base = s; base < e; base += 64) {
    int cnt = e - base; if (cnt > 64) cnt = 64;
    int ci = csr[base + (lane < cnt ? lane : cnt - 1)];
    int j = 0;
    for (; j + 15 < cnt; j += 16) {
      int i0 = __shfl(ci, j + q);
      int i1 = __shfl(ci, j + 4 + q);
      int i2 = __shfl(ci, j + 8 + q);
      int i3 = __shfl(ci, j + 12 + q);
      bf16x8 v0 = *(const bf16x8*)(xb + (size_t)i0 * 128 + p * 8);
      bf16x8 v1 = *(const bf16x8*)(xb + (size_t)i1 * 128 + p * 8);
      bf16x8 v2 = *(const bf16x8*)(xb + (size_t)i2 * 128 + p * 8);
      bf16x8 v3 = *(const bf16x8*)(xb + (size_t)i3 * 128 + p * 8);
#pragma unroll
      for (int k = 0; k < 8; ++k) {
        acc[0][k] += bf2f((ushort)v0[k]);
        acc[1][k] += bf2f((ushort)v1[k]);
        acc[2][k] += bf2f((ushort)v2[k]);
        acc[3][k] += bf2f((ushort)v3[k]);
      }
    }
    for (; j + 3 < cnt; j += 4) {
      int i0 = __shfl(ci, j + q);
      bf16x8 v0 = *(const bf16x8*)(xb + (size_t)i0 * 128 + p * 8);
#pragma unroll
      for (int k = 0; k < 8; ++k) acc[0][k] += bf2f((ushort)v0[k]);
    }
    if (j < cnt) {
      int sel = j + q;
      int i0 = __shfl(ci, sel < cnt ? sel : j);
      bf16x8 v0 = *(const bf16x8*)(xb + (size_t)i0 * 128 + p * 8);
      if (sel < cnt) {
#pragma unroll
        for (int k = 0; k < 8; ++k) acc[0][k] += bf2f((ushort)v0[k]);
      }
    }
  }
  float c8[8];
#pragma unroll
  for (int k = 0; k < 8; ++k) {
    float v = (acc[0][k] + acc[1][k]) + (acc[2][k] + acc[3][k]);
    v += __shfl_xor(v, 16);
    v += __shfl_xor(v, 32);
    c8[k] = v;
  }
  if (q == 0) {
    float inv = inv_deg[n];
    bf16x8 o;
#pragma unroll
    for (int k = 0; k < 8; ++k) o[k] = (short)f2bf(c8[k] * inv);
    *(bf16x8*)(agg1b + (size_t)n * 128 + p * 8) = o;
  }
}

// Fused MFMA MLP: g = relu(agg1 @ W1T + b1) @ W2T, bf16 in/out, fp32 accum.
__global__ void __launch_bounds__(256) k_mlp(const ushort* __restrict__ agg1b, const bf16x8* __restrict__ w1f,
                                             const float* __restrict__ b1, const bf16x8* __restrict__ w2f,
                                             ushort* __restrict__ gb, int N) {
  __shared__ __align__(16) ushort sm[16896];  // 33792 B
  ushort* aT = sm;   // phase1: [64][136]  (272B row stride -> 2-way bank alias, free)
  ushort* hT = sm;   // phase2: [64][264]  (528B row stride -> 2-way)
  const int t = threadIdx.x;
  const int n0 = blockIdx.x * 64;

  // Stage A tile: 64 rows x 128 bf16 = 1024 x bf16x8 chunks, 16B loads, coalesced.
#pragma unroll
  for (int i = 0; i < 4; ++i) {
    int idx = i * 256 + t;            // 1024 x 16B
    int row = idx >> 4, c8 = idx & 15;
    int rr = n0 + row; if (rr >= N) rr = N - 1;
    bf16x8 v = *(const bf16x8*)(agg1b + (size_t)rr * 128 + c8 * 8);
    *(bf16x8*)(aT + row * 136 + c8 * 8) = v;
  }
  __syncthreads();

  const int w = t >> 6, l = t & 63;
  const int lm = l & 15, lq = l >> 4;

  f32x4 acc[4][4];
#pragma unroll
  for (int mt = 0; mt < 4; ++mt)
#pragma unroll
    for (int nt = 0; nt < 4; ++nt) acc[mt][nt] = (f32x4)(0.f);

#pragma unroll
  for (int kt = 0; kt < 4; ++kt) {
    bf16x8 b[4], a[4];
#pragma unroll
    for (int nt = 0; nt < 4; ++nt)
      b[nt] = w1f[((w * 4 + nt) * 4 + kt) * 64 + l];
#pragma unroll
    for (int mt = 0; mt < 4; ++mt)
      a[mt] = *(const bf16x8*)(aT + (mt * 16 + lm) * 136 + kt * 32 + lq * 8);
#pragma unroll
    for (int mt = 0; mt < 4; ++mt)
#pragma unroll
      for (int nt = 0; nt < 4; ++nt)
        acc[mt][nt] = __builtin_amdgcn_mfma_f32_16x16x32_bf16(a[mt], b[nt], acc[mt][nt], 0, 0, 0);
  }
  __syncthreads();  // all aT reads done before hT overwrites

  // Epilogue 1: h = relu(acc + b1) -> hT (bf16). C/D layout: col=lane&15, row=lq*4+reg.
#pragma unroll
  for (int nt = 0; nt < 4; ++nt) {
    int col = w * 64 + nt * 16 + lm;
    float bb = b1[col];
#pragma unroll
    for (int mt = 0; mt < 4; ++mt)
#pragma unroll
      for (int r = 0; r < 4; ++r) {
        int row = mt * 16 + lq * 4 + r;
        float hv = acc[mt][nt][r] + bb;
        hT[row * 264 + col] = f2bf(fmaxf(hv, 0.f));
      }
  }
  __syncthreads();

  // Phase 2: g[64][64] = hT @ W2T. Wave w: rows [16w,16w+16), K=256.
  f32x4 acc2[4];
#pragma unroll
  for (int ot = 0; ot < 4; ++ot) acc2[ot] = (f32x4)(0.f);
#pragma unroll
  for (int kt = 0; kt < 8; ++kt) {
    bf16x8 a2 = *(const bf16x8*)(hT + (w * 16 + lm) * 264 + kt * 32 + lq * 8);
#pragma unroll
    for (int ot = 0; ot < 4; ++ot) {
      bf16x8 bf = w2f[(ot * 8 + kt) * 64 + l];
      acc2[ot] = __builtin_amdgcn_mfma_f32_16x16x32_bf16(a2, bf, acc2[ot], 0, 0, 0);
    }
  }
  // Epilogue 2: write g bf16.
#pragma unroll
  for (int ot = 0; ot < 4; ++ot)
#pragma unroll
    for (int r = 0; r < 4; ++r) {
      int row = n0 + w * 16 + lq * 4 + r;
      if (row < N) gb[(size_t)row * 64 + ot * 16 + lm] = f2bf(acc2[ot][r]);
    }
}

// agg2 + b2 + log_softmax fused. Wave per node; quarter-wave (16 lanes x ushort4 = 128B)
// per edge; shfl-distributed csr indices (no vmcnt serialization).
__global__ void __launch_bounds__(256) k_agg2(const ushort* __restrict__ gb, const int* __restrict__ csr,
                                              const int* __restrict__ row_ptr, const float* __restrict__ inv_deg,
                                              const float* __restrict__ b2, float* __restrict__ out, int N) {
  int n = blockIdx.x * 4 + (threadIdx.x >> 6);
  if (n >= N) return;
  int lane = threadIdx.x & 63;
  int q = lane >> 4, p = lane & 15;
  int s = row_ptr[n], e = row_ptr[n + 1];
  float acc[4][4];
#pragma unroll
  for (int c = 0; c < 4; ++c)
#pragma unroll
    for (int k = 0; k < 4; ++k) acc[c][k] = 0.f;

  for (int base = s; base < e; base += 64) {
    int cnt = e - base; if (cnt > 64) cnt = 64;
    int ci = csr[base + (lane < cnt ? lane : cnt - 1)];
    int j = 0;
    for (; j + 15 < cnt; j += 16) {
      int i0 = __shfl(ci, j + q);
      int i1 = __shfl(ci, j + 4 + q);
      int i2 = __shfl(ci, j + 8 + q);
      int i3 = __shfl(ci, j + 12 + q);
      ushort4 v0 = *(const ushort4*)(gb + (size_t)i0 * 64 + p * 4);
      ushort4 v1 = *(const ushort4*)(gb + (size_t)i1 * 64 + p * 4);
      ushort4 v2 = *(const ushort4*)(gb + (size_t)i2 * 64 + p * 4);
      ushort4 v3 = *(const ushort4*)(gb + (size_t)i3 * 64 + p * 4);
      acc[0][0] += bf2f(v0.x); acc[0][1] += bf2f(v0.y); acc[0][2] += bf2f(v0.z); acc[0][3] += bf2f(v0.w);
      acc[1][0] += bf2f(v1.x); acc[1][1] += bf2f(v1.y); acc[1][2] += bf2f(v1.z); acc[1][3] += bf2f(v1.w);
      acc[2][0] += bf2f(v2.x); acc[2][1] += bf2f(v2.y); acc[2][2] += bf2f(v2.z); acc[2][3] += bf2f(v2.w);
      acc[3][0] += bf2f(v3.x); acc[3][1] += bf2f(v3.y); acc[3][2] += bf2f(v3.z); acc[3][3] += bf2f(v3.w);
    }
    for (; j + 3 < cnt; j += 4) {
      int i0 = __shfl(ci, j + q);
      ushort4 v0 = *(const ushort4*)(gb + (size_t)i0 * 64 + p * 4);
      acc[0][0] += bf2f(v0.x); acc[0][1] += bf2f(v0.y); acc[0][2] += bf2f(v0.z); acc[0][3] += bf2f(v0.w);
    }
    if (j < cnt) {
      int sel = j + q;
      int i0 = __shfl(ci, sel < cnt ? sel : j);
      ushort4 v0 = *(const ushort4*)(gb + (size_t)i0 * 64 + p * 4);
      if (sel < cnt) {
        acc[0][0] += bf2f(v0.x); acc[0][1] += bf2f(v0.y); acc[0][2] += bf2f(v0.z); acc[0][3] += bf2f(v0.w);
      }
    }
  }
  float ax = (acc[0][0] + acc[1][0]) + (acc[2][0] + acc[3][0]);
  float ay = (acc[0][1] + acc[1][1]) + (acc[2][1] + acc[3][1]);
  float az = (acc[0][2] + acc[1][2]) + (acc[2][2] + acc[3][2]);
  float aw = (acc[0][3] + acc[1][3]) + (acc[2][3] + acc[3][3]);
  ax += __shfl_xor(ax, 16); ay += __shfl_xor(ay, 16);
  az += __shfl_xor(az, 16); aw += __shfl_xor(aw, 16);
  ax += __shfl_xor(ax, 32); ay += __shfl_xor(ay, 32);
  az += __shfl_xor(az, 32); aw += __shfl_xor(aw, 32);
  float inv = inv_deg[n];
  float4 b = *(const float4*)(b2 + p * 4);
  float4 v;
  v.x = ax * inv + b.x;
  v.y = ay * inv + b.y;
  v.z = az * inv + b.z;
  v.w = aw * inv + b.w;
  float mx = fmaxf(fmaxf(v.x, v.y), fmaxf(v.z, v.w));
#pragma unroll
  for (int off = 1; off <= 8; off <<= 1) mx = fmaxf(mx, __shfl_xor(mx, off));
  float se = expf(v.x - mx) + expf(v.y - mx) + expf(v.z - mx) + expf(v.w - mx);
#pragma unroll
  for (int off = 1; off <= 8; off <<= 1) se += __shfl_xor(se, off);
  float lse = mx + logf(se);
  v.x -= lse; v.y -= lse; v.z -= lse; v.w -= lse;
  if (q == 0) *(float4*)(out + (size_t)n * 64 + p * 4) = v;
}

extern "C" void kernel_launch(void* const* d_in, const int* in_sizes, int n_in,
                              void* d_out, int out_size, void* d_ws, size_t ws_size,
                              hipStream_t stream) {
  const float* x  = (const float*)d_in[0];
  const int*   ei = (const int*)d_in[1];
  const float* W1 = (const float*)d_in[2];
  const float* b1 = (const float*)d_in[3];
  const float* W2 = (const float*)d_in[4];
  const float* b2 = (const float*)d_in[5];
  float* out = (float*)d_out;
  const int N = in_sizes[0] / 128;  // 100000
  const int E = in_sizes[1] / 2;    // 1600000
  const int NB = (N + BMASK) >> BSHIFT;  // 98

  char* base = (char*)d_ws;
  size_t off = 0;
  auto alloc = [&](size_t bytes) -> char* {
    char* p = base + off;
    off += (bytes + 255) & ~(size_t)255;
    return p;
  };
  int*    flag    = (int*)alloc(4);
  int*    bcnt    = (int*)alloc((size_t)NB * 4);
  int*    bbase   = (int*)alloc((size_t)(NB + 1) * 4);
  int*    bcur    = (int*)alloc((size_t)NB * 4);
  int*    gpair   = (int*)alloc((size_t)E * 4);
  int*    row_ptr = (int*)alloc((size_t)(N + 1) * 4);
  float*  inv_deg = (float*)alloc((size_t)N * 4);
  int*    csr     = (int*)alloc((size_t)E * 4);
  ushort* xb      = (ushort*)alloc((size_t)N * 128 * 2);
  ushort* W1f     = (ushort*)alloc((size_t)32768 * 2);
  ushort* W2f     = (ushort*)alloc((size_t)16384 * 2);
  ushort* agg1b   = (ushort*)alloc((size_t)N * 128 * 2);
  ushort* gb      = (ushort*)alloc((size_t)N * 64 * 2);
  (void)ws_size; (void)n_in; (void)out_size;

  hipMemsetAsync(bcnt, 0, (size_t)NB * 4, stream);
  k_detect<<<1, 64, 0, stream>>>(ei, flag);
  k_prep_x<<<(N * 128 / 4 + 255) / 256, 256, 0, stream>>>((const float4*)x, (ushort4*)xb, N * 128 / 4);
  k_prep_w<<<192, 256, 0, stream>>>(W1, W2, W1f, W2f);
  k_bhist<<<512, 256, 0, stream>>>(ei, flag, bcnt, E, NB);
  k_bscan<<<1, 128, 0, stream>>>(bcnt, bbase, bcur, row_ptr, NB, N, E);
  k_bin<<<(E + TBIN - 1) / TBIN, 256, 0, stream>>>(ei, flag, bcur, gpair, E, NB);
  k_bcsr<<<NB, 1024, 0, stream>>>(gpair, bbase, row_ptr, inv_deg, csr, N);
  k_agg1<<<(N + 3) / 4, 256, 0, stream>>>(xb, csr, row_ptr, inv_deg, agg1b, N);
  k_mlp<<<(N + 63) / 64, 256, 0, stream>>>(agg1b, (const bf16x8*)W1f, b1, (const bf16x8*)W2f, gb, N);
  k_agg2<<<(N + 3) / 4, 256, 0, stream>>>(gb, csr, row_ptr, inv_deg, b2, out, N);
}